// Round 1
// baseline (3404.144 us; speedup 1.0000x reference)
//
#include <hip/hip_runtime.h>
#include <math.h>

#define HWB 65536
#define NPIX 524288   // 8*256*256

// ---------- kernel 1: collapse offset head:  Wcomb[p][cin][tap] = sum_c Woff2[p,c]*Woff1[c,cin,tap]
__global__ void build_wcomb_kernel(const float* __restrict__ Woff1,
                                   const float* __restrict__ boff1,
                                   const float* __restrict__ Woff2,
                                   float* __restrict__ wcomb,
                                   float* __restrict__ bcomb) {
    int idx = blockIdx.x * 256 + threadIdx.x;
    if (idx < 2 * 64 * 25) {
        int p = idx / 1600;
        int rest = idx - p * 1600;      // cin*25 + tap
        float s = 0.f;
        for (int cm = 0; cm < 64; ++cm)
            s += Woff2[p * 64 + cm] * Woff1[cm * 1600 + rest];
        wcomb[idx] = s;
    }
    if (idx < 2) {
        float s = 0.f;
        for (int cm = 0; cm < 64; ++cm) s += Woff2[idx * 64 + cm] * boff1[cm];
        bcomb[idx] = s;
    }
}

// ---------- kernel 2: generic per-pixel 1x1 conv (64x64 matvec).
// in: [NPIX][64] contiguous. PLANAR=1 -> out[(b*64+c)*HW + hw]; PLANAR=0 -> out[pix*64+c].
template <int PLANAR>
__global__ __launch_bounds__(256)
void conv1x1_kernel(const float* __restrict__ in, const float* __restrict__ Wg,
                    const float* __restrict__ bias, float* __restrict__ out) {
    __shared__ float Wl[4096];
    __shared__ float xT[64][64];
    int t = threadIdx.x;
    for (int i = t; i < 4096; i += 256) Wl[i] = Wg[i];
    int p = t & 63, j = t >> 6;
    int pix = blockIdx.x * 64 + p;
    const float4* src = (const float4*)(in + (size_t)pix * 64 + j * 16);
#pragma unroll
    for (int q4 = 0; q4 < 4; ++q4) {
        float4 v = src[q4];
        int kk = j * 16 + q4 * 4;
        xT[kk][p] = v.x; xT[kk + 1][p] = v.y; xT[kk + 2][p] = v.z; xT[kk + 3][p] = v.w;
    }
    __syncthreads();
    float sv[64];
#pragma unroll
    for (int kk = 0; kk < 64; ++kk) sv[kk] = xT[kk][p];
    float acc[16];
#pragma unroll
    for (int u = 0; u < 16; ++u) {
        int c = j * 16 + u;
        float a = bias[c];
        const float4* wrow = (const float4*)(Wl + c * 64);
#pragma unroll
        for (int k4 = 0; k4 < 16; ++k4) {
            float4 w = wrow[k4];
            a += w.x * sv[4 * k4] + w.y * sv[4 * k4 + 1] + w.z * sv[4 * k4 + 2] + w.w * sv[4 * k4 + 3];
        }
        acc[u] = a;
    }
    if (PLANAR) {
        int b = pix >> 16, hw = pix & 65535;
#pragma unroll
        for (int u = 0; u < 16; ++u) {
            int c = j * 16 + u;
            out[((size_t)(b * 64 + c) << 16) + hw] = acc[u];
        }
    } else {
#pragma unroll
        for (int u = 0; u < 16; ++u) out[(size_t)pix * 64 + j * 16 + u] = acc[u];
    }
}

// ---------- kernel 3: offsets via collapsed 5x5 conv, then sample coords
__global__ __launch_bounds__(256)
void offset_kernel(const float* __restrict__ q, const float* __restrict__ wcomb,
                   const float* __restrict__ bcomb, float2* __restrict__ coords) {
    __shared__ float qt[64][400];   // [c][20y*20x], 102.4 KB
    __shared__ float wc[3200];
    int t = threadIdx.x;
    for (int i = t; i < 3200; i += 256) wc[i] = wcomb[i];
    int bx = blockIdx.x * 16, by = blockIdx.y * 16, b = blockIdx.z;
    const float* qb = q + (((size_t)b * 64) << 16);
    for (int i = t; i < 25600; i += 256) {
        int c = i / 400, rem = i - c * 400;
        int yy = rem / 20, xx = rem - yy * 20;
        int gy = by - 2 + yy, gx = bx - 2 + xx;
        float v = 0.f;
        if (gy >= 0 && gy < 256 && gx >= 0 && gx < 256)
            v = qb[((size_t)c << 16) + gy * 256 + gx];
        qt[c][rem] = v;
    }
    __syncthreads();
    int px = t & 15, py = t >> 4;
    float a0 = bcomb[0], a1 = bcomb[1];
    for (int c = 0; c < 64; ++c) {
#pragma unroll
        for (int tap = 0; tap < 25; ++tap) {
            int dy = tap / 5, dx = tap % 5;
            float qv = qt[c][(py + dy) * 20 + px + dx];
            a0 += wc[c * 25 + tap] * qv;
            a1 += wc[1600 + c * 25 + tap] * qv;
        }
    }
    float ox = tanhf(a0) * 5.f, oy = tanhf(a1) * 5.f;
    float vgx = (float)(bx + px) + ox, vgy = (float)(by + py) + oy;
    // ix = ((2*vg/255 - 1 + 1)*256 - 1)*0.5 = vg*256/255 - 0.5
    float ix = vgx * (256.f / 255.f) - 0.5f;
    float iy = vgy * (256.f / 255.f) - 0.5f;
    coords[((size_t)b << 16) + (by + py) * 256 + bx + px] = make_float2(ix, iy);
}

// ---------- kernel 4: bilinear sample (zeros padding) + k/v 1x1 convs + rpb
__global__ __launch_bounds__(256)
void sample_kv_kernel(const float* __restrict__ x, const float2* __restrict__ coords,
                      const float* __restrict__ Wk, const float* __restrict__ bk,
                      const float* __restrict__ Wv, const float* __restrict__ bv,
                      const float* __restrict__ rpb,
                      float* __restrict__ kout, float* __restrict__ vout) {
    __shared__ float Wkl[4096], Wvl[4096];
    __shared__ float sT[64][64];
    int t = threadIdx.x;
    for (int i = t; i < 4096; i += 256) { Wkl[i] = Wk[i]; Wvl[i] = Wv[i]; }
    int p = t & 63, j = t >> 6;
    int pix = blockIdx.x * 64 + p;
    int b = pix >> 16, hw = pix & 65535, h = hw >> 8;
    float2 cc = coords[pix];
    float ix0f = floorf(cc.x), iy0f = floorf(cc.y);
    float wx1 = cc.x - ix0f, wy1 = cc.y - iy0f;
    float wx0 = 1.f - wx1, wy0 = 1.f - wy1;
    int ix0 = (int)ix0f, iy0 = (int)iy0f;
    float s[16];
#pragma unroll
    for (int u = 0; u < 16; ++u) s[u] = 0.f;
    const float* xb = x + (((size_t)b) << 16) * 64 + j * 16;
    int cxs[4] = {ix0, ix0 + 1, ix0, ix0 + 1};
    int cys[4] = {iy0, iy0, iy0 + 1, iy0 + 1};
    float ws4[4] = {wx0 * wy0, wx1 * wy0, wx0 * wy1, wx1 * wy1};
#pragma unroll
    for (int cr = 0; cr < 4; ++cr) {
        int cx = cxs[cr], cy = cys[cr];
        if (cx >= 0 && cx < 256 && cy >= 0 && cy < 256) {
            float wgt = ws4[cr];
            const float4* sp = (const float4*)(xb + ((size_t)(cy * 256 + cx) << 6));
#pragma unroll
            for (int q4 = 0; q4 < 4; ++q4) {
                float4 v = sp[q4];
                s[4 * q4] += wgt * v.x; s[4 * q4 + 1] += wgt * v.y;
                s[4 * q4 + 2] += wgt * v.z; s[4 * q4 + 3] += wgt * v.w;
            }
        }
    }
#pragma unroll
    for (int u = 0; u < 16; ++u) sT[j * 16 + u][p] = s[u];
    __syncthreads();
    float sv[64];
#pragma unroll
    for (int kk = 0; kk < 64; ++kk) sv[kk] = sT[kk][p];
#pragma unroll
    for (int u = 0; u < 16; ++u) {
        int c = j * 16 + u;
        float ak = bk[c];
        float av = bv[c] + rpb[c * 256 + h];
        const float4* wkr = (const float4*)(Wkl + c * 64);
        const float4* wvr = (const float4*)(Wvl + c * 64);
#pragma unroll
        for (int k4 = 0; k4 < 16; ++k4) {
            float4 w1 = wkr[k4], w2 = wvr[k4];
            ak += w1.x * sv[4 * k4] + w1.y * sv[4 * k4 + 1] + w1.z * sv[4 * k4 + 2] + w1.w * sv[4 * k4 + 3];
            av += w2.x * sv[4 * k4] + w2.y * sv[4 * k4 + 1] + w2.z * sv[4 * k4 + 2] + w2.w * sv[4 * k4 + 3];
        }
        size_t o = ((size_t)(b * 64 + c) << 16) + hw;
        kout[o] = ak;
        vout[o] = av;
    }
}

// ---------- kernel 5: per-head attention, 64-row tile per block, O written in-place over q
__global__ __launch_bounds__(512)
void attn_kernel(float* __restrict__ qo, const float* __restrict__ kbuf,
                 const float* __restrict__ vbuf) {
    __shared__ float qs[64][257];   // q tile, later reused to stage O
    __shared__ float ss[64][257];   // scores -> exp(scores)
    __shared__ float red[64][8];
    int t = threadIdx.x;
    int i = t & 63, g = t >> 6;                 // row i, col-group g (32 cols each)
    int hd = blockIdx.x, rt = blockIdx.y;
    size_t qbase = ((size_t)hd * 256 + rt * 64) * 256;
    const float4* qb4 = (const float4*)(qo + qbase);
    for (int idx = t; idx < 4096; idx += 512) {
        float4 v = qb4[idx];
        int row = idx >> 6, col = (idx & 63) * 4;
        qs[row][col] = v.x; qs[row][col + 1] = v.y; qs[row][col + 2] = v.z; qs[row][col + 3] = v.w;
    }
    __syncthreads();
    const float* kb = kbuf + ((size_t)hd << 16);
    // S = q k^T * 0.125 : thread (i,g) -> S[i][g*32 .. g*32+31]
    for (int dblk = 0; dblk < 4; ++dblk) {
        float qreg[64];
#pragma unroll
        for (int d = 0; d < 64; ++d) qreg[d] = qs[i][dblk * 64 + d];
        for (int jj = 0; jj < 32; ++jj) {
            int jrow = g * 32 + jj;
            const float4* krow = (const float4*)(kb + jrow * 256 + dblk * 64);
            float a0 = 0, a1 = 0, a2 = 0, a3 = 0;
#pragma unroll
            for (int k4 = 0; k4 < 16; ++k4) {
                float4 kv = krow[k4];
                a0 += kv.x * qreg[4 * k4];     a1 += kv.y * qreg[4 * k4 + 1];
                a2 += kv.z * qreg[4 * k4 + 2]; a3 += kv.w * qreg[4 * k4 + 3];
            }
            float part = ((a0 + a1) + (a2 + a3)) * 0.125f;
            if (dblk == 0) ss[i][jrow] = part;
            else ss[i][jrow] += part;
        }
    }
    __syncthreads();
    // softmax over row i (cross-group reduce through LDS)
    float m = -1e30f;
    for (int jj = 0; jj < 32; ++jj) m = fmaxf(m, ss[i][g * 32 + jj]);
    red[i][g] = m;
    __syncthreads();
    m = red[i][0];
#pragma unroll
    for (int gg = 1; gg < 8; ++gg) m = fmaxf(m, red[i][gg]);
    __syncthreads();
    float lsum = 0.f;
    for (int jj = 0; jj < 32; ++jj) {
        float e = __expf(ss[i][g * 32 + jj] - m);
        ss[i][g * 32 + jj] = e;
        lsum += e;
    }
    red[i][g] = lsum;
    __syncthreads();
    float l = 0.f;
#pragma unroll
    for (int gg = 0; gg < 8; ++gg) l += red[i][gg];
    float inv = 1.f / l;
    // O = (exp(S) @ V) * inv : thread (i,g) -> O[i][g*32 .. +31]
    const float* vb = vbuf + ((size_t)hd << 16);
    float ov[32];
#pragma unroll
    for (int d = 0; d < 32; ++d) ov[d] = 0.f;
    for (int jrow = 0; jrow < 256; ++jrow) {
        float pv = ss[i][jrow];
        const float4* vrow = (const float4*)(vb + jrow * 256 + g * 32);
#pragma unroll
        for (int d4 = 0; d4 < 8; ++d4) {
            float4 vv = vrow[d4];
            ov[4 * d4] += pv * vv.x;     ov[4 * d4 + 1] += pv * vv.y;
            ov[4 * d4 + 2] += pv * vv.z; ov[4 * d4 + 3] += pv * vv.w;
        }
    }
    // stage O into qs (q dead), then coalesced store in-place over q rows
#pragma unroll
    for (int d = 0; d < 32; ++d) qs[i][g * 32 + d] = ov[d] * inv;
    __syncthreads();
    float* ob = qo + qbase;
    for (int idx = t; idx < 16384; idx += 512) {
        int row = idx >> 8, col = idx & 255;
        ob[idx] = qs[row][col];
    }
}

extern "C" void kernel_launch(void* const* d_in, const int* in_sizes, int n_in,
                              void* d_out, int out_size, void* d_ws, size_t ws_size,
                              hipStream_t stream) {
    const float* x     = (const float*)d_in[0];
    const float* Wq    = (const float*)d_in[1];
    const float* bq    = (const float*)d_in[2];
    const float* Wk    = (const float*)d_in[3];
    const float* bk    = (const float*)d_in[4];
    const float* Wv    = (const float*)d_in[5];
    const float* bv    = (const float*)d_in[6];
    const float* Woff1 = (const float*)d_in[7];
    const float* boff1 = (const float*)d_in[8];
    const float* Woff2 = (const float*)d_in[9];
    const float* rpb   = (const float*)d_in[10];
    const float* Wout  = (const float*)d_in[11];
    const float* bout  = (const float*)d_in[12];
    float* out = (float*)d_out;

    float* ws     = (float*)d_ws;
    float* qbuf   = ws;                              // NPIX*64 floats (later holds attn out)
    float* kbuf   = qbuf + (size_t)NPIX * 64;
    float* vbuf   = kbuf + (size_t)NPIX * 64;
    float* coords = vbuf + (size_t)NPIX * 64;        // NPIX float2
    float* wcomb  = coords + (size_t)NPIX * 2;       // 3200
    float* bcomb  = wcomb + 3200;                    // 2

    build_wcomb_kernel<<<13, 256, 0, stream>>>(Woff1, boff1, Woff2, wcomb, bcomb);
    conv1x1_kernel<1><<<NPIX / 64, 256, 0, stream>>>(x, Wq, bq, qbuf);
    offset_kernel<<<dim3(16, 16, 8), 256, 0, stream>>>(qbuf, wcomb, bcomb, (float2*)coords);
    sample_kv_kernel<<<NPIX / 64, 256, 0, stream>>>(x, (const float2*)coords, Wk, bk, Wv, bv,
                                                    rpb, kbuf, vbuf);
    attn_kernel<<<dim3(512, 4), 512, 0, stream>>>(qbuf, kbuf, vbuf);
    conv1x1_kernel<0><<<NPIX / 64, 256, 0, stream>>>(qbuf, Wout, bout, out);
}

// Round 2
// 1356.342 us; speedup vs baseline: 2.5098x; 2.5098x over previous
//
#include <hip/hip_runtime.h>
#include <math.h>

#define HWB 65536
#define NPIX 524288   // 8*256*256

typedef __attribute__((ext_vector_type(8))) short short8b;
typedef __attribute__((ext_vector_type(4))) float f32x4;
#define MFMA16 __builtin_amdgcn_mfma_f32_16x16x32_bf16

__device__ inline unsigned short bf16_rn(float x) {
    unsigned u = __float_as_uint(x);
    unsigned r = (u + 0x7FFFu + ((u >> 16) & 1u)) >> 16;
    return (unsigned short)r;
}
__device__ inline float bf16_f(unsigned short h) {
    return __uint_as_float(((unsigned)h) << 16);
}

// ---------- kernel 1: collapse offset head
__global__ void build_wcomb_kernel(const float* __restrict__ Woff1,
                                   const float* __restrict__ boff1,
                                   const float* __restrict__ Woff2,
                                   float* __restrict__ wcomb,
                                   float* __restrict__ bcomb) {
    int idx = blockIdx.x * 256 + threadIdx.x;
    if (idx < 2 * 64 * 25) {
        int p = idx / 1600;
        int rest = idx - p * 1600;
        float s = 0.f;
        for (int cm = 0; cm < 64; ++cm)
            s += Woff2[p * 64 + cm] * Woff1[cm * 1600 + rest];
        wcomb[idx] = s;
    }
    if (idx < 2) {
        float s = 0.f;
        for (int cm = 0; cm < 64; ++cm) s += Woff2[idx * 64 + cm] * boff1[cm];
        bcomb[idx] = s;
    }
}

// ---------- kernel 2: per-pixel 1x1 conv (64x64 matvec)
template <int PLANAR>
__global__ __launch_bounds__(256)
void conv1x1_kernel(const float* __restrict__ in, const float* __restrict__ Wg,
                    const float* __restrict__ bias, float* __restrict__ out) {
    __shared__ float Wl[4096];
    __shared__ float xT[64][64];
    int t = threadIdx.x;
    for (int i = t; i < 4096; i += 256) Wl[i] = Wg[i];
    int p = t & 63, j = t >> 6;
    int pix = blockIdx.x * 64 + p;
    const float4* src = (const float4*)(in + (size_t)pix * 64 + j * 16);
#pragma unroll
    for (int q4 = 0; q4 < 4; ++q4) {
        float4 v = src[q4];
        int kk = j * 16 + q4 * 4;
        xT[kk][p] = v.x; xT[kk + 1][p] = v.y; xT[kk + 2][p] = v.z; xT[kk + 3][p] = v.w;
    }
    __syncthreads();
    float sv[64];
#pragma unroll
    for (int kk = 0; kk < 64; ++kk) sv[kk] = xT[kk][p];
    float acc[16];
#pragma unroll
    for (int u = 0; u < 16; ++u) {
        int c = j * 16 + u;
        float a = bias[c];
        const float4* wrow = (const float4*)(Wl + c * 64);
#pragma unroll
        for (int k4 = 0; k4 < 16; ++k4) {
            float4 w = wrow[k4];
            a += w.x * sv[4 * k4] + w.y * sv[4 * k4 + 1] + w.z * sv[4 * k4 + 2] + w.w * sv[4 * k4 + 3];
        }
        acc[u] = a;
    }
    if (PLANAR) {
        int b = pix >> 16, hw = pix & 65535;
#pragma unroll
        for (int u = 0; u < 16; ++u) {
            int c = j * 16 + u;
            out[((size_t)(b * 64 + c) << 16) + hw] = acc[u];
        }
    } else {
#pragma unroll
        for (int u = 0; u < 16; ++u) out[(size_t)pix * 64 + j * 16 + u] = acc[u];
    }
}

// ---------- kernel 3: offsets via collapsed 5x5 conv, then sample coords
__global__ __launch_bounds__(256)
void offset_kernel(const float* __restrict__ q, const float* __restrict__ wcomb,
                   const float* __restrict__ bcomb, float2* __restrict__ coords) {
    __shared__ float qt[64][400];
    __shared__ float wc[3200];
    int t = threadIdx.x;
    for (int i = t; i < 3200; i += 256) wc[i] = wcomb[i];
    int bx = blockIdx.x * 16, by = blockIdx.y * 16, b = blockIdx.z;
    const float* qb = q + (((size_t)b * 64) << 16);
    for (int i = t; i < 25600; i += 256) {
        int c = i / 400, rem = i - c * 400;
        int yy = rem / 20, xx = rem - yy * 20;
        int gy = by - 2 + yy, gx = bx - 2 + xx;
        float v = 0.f;
        if (gy >= 0 && gy < 256 && gx >= 0 && gx < 256)
            v = qb[((size_t)c << 16) + gy * 256 + gx];
        qt[c][rem] = v;
    }
    __syncthreads();
    int px = t & 15, py = t >> 4;
    float a0 = bcomb[0], a1 = bcomb[1];
    for (int c = 0; c < 64; ++c) {
#pragma unroll
        for (int tap = 0; tap < 25; ++tap) {
            int dy = tap / 5, dx = tap % 5;
            float qv = qt[c][(py + dy) * 20 + px + dx];
            a0 += wc[c * 25 + tap] * qv;
            a1 += wc[1600 + c * 25 + tap] * qv;
        }
    }
    float ox = tanhf(a0) * 5.f, oy = tanhf(a1) * 5.f;
    float vgx = (float)(bx + px) + ox, vgy = (float)(by + py) + oy;
    float ix = vgx * (256.f / 255.f) - 0.5f;
    float iy = vgy * (256.f / 255.f) - 0.5f;
    coords[((size_t)b << 16) + (by + py) * 256 + bx + px] = make_float2(ix, iy);
}

// ---------- kernel 4: bilinear sample + k/v 1x1 convs + rpb
__global__ __launch_bounds__(256)
void sample_kv_kernel(const float* __restrict__ x, const float2* __restrict__ coords,
                      const float* __restrict__ Wk, const float* __restrict__ bk,
                      const float* __restrict__ Wv, const float* __restrict__ bv,
                      const float* __restrict__ rpb,
                      float* __restrict__ kout, float* __restrict__ vout) {
    __shared__ float Wkl[4096], Wvl[4096];
    __shared__ float sT[64][64];
    int t = threadIdx.x;
    for (int i = t; i < 4096; i += 256) { Wkl[i] = Wk[i]; Wvl[i] = Wv[i]; }
    int p = t & 63, j = t >> 6;
    int pix = blockIdx.x * 64 + p;
    int b = pix >> 16, hw = pix & 65535, h = hw >> 8;
    float2 cc = coords[pix];
    float ix0f = floorf(cc.x), iy0f = floorf(cc.y);
    float wx1 = cc.x - ix0f, wy1 = cc.y - iy0f;
    float wx0 = 1.f - wx1, wy0 = 1.f - wy1;
    int ix0 = (int)ix0f, iy0 = (int)iy0f;
    float s[16];
#pragma unroll
    for (int u = 0; u < 16; ++u) s[u] = 0.f;
    const float* xb = x + (((size_t)b) << 16) * 64 + j * 16;
    int cxs[4] = {ix0, ix0 + 1, ix0, ix0 + 1};
    int cys[4] = {iy0, iy0, iy0 + 1, iy0 + 1};
    float ws4[4] = {wx0 * wy0, wx1 * wy0, wx0 * wy1, wx1 * wy1};
#pragma unroll
    for (int cr = 0; cr < 4; ++cr) {
        int cx = cxs[cr], cy = cys[cr];
        if (cx >= 0 && cx < 256 && cy >= 0 && cy < 256) {
            float wgt = ws4[cr];
            const float4* sp = (const float4*)(xb + ((size_t)(cy * 256 + cx) << 6));
#pragma unroll
            for (int q4 = 0; q4 < 4; ++q4) {
                float4 v = sp[q4];
                s[4 * q4] += wgt * v.x; s[4 * q4 + 1] += wgt * v.y;
                s[4 * q4 + 2] += wgt * v.z; s[4 * q4 + 3] += wgt * v.w;
            }
        }
    }
#pragma unroll
    for (int u = 0; u < 16; ++u) sT[j * 16 + u][p] = s[u];
    __syncthreads();
    float sv[64];
#pragma unroll
    for (int kk = 0; kk < 64; ++kk) sv[kk] = sT[kk][p];
#pragma unroll
    for (int u = 0; u < 16; ++u) {
        int c = j * 16 + u;
        float ak = bk[c];
        float av = bv[c] + rpb[c * 256 + h];
        const float4* wkr = (const float4*)(Wkl + c * 64);
        const float4* wvr = (const float4*)(Wvl + c * 64);
#pragma unroll
        for (int k4 = 0; k4 < 16; ++k4) {
            float4 w1 = wkr[k4], w2 = wvr[k4];
            ak += w1.x * sv[4 * k4] + w1.y * sv[4 * k4 + 1] + w1.z * sv[4 * k4 + 2] + w1.w * sv[4 * k4 + 3];
            av += w2.x * sv[4 * k4] + w2.y * sv[4 * k4 + 1] + w2.z * sv[4 * k4 + 2] + w2.w * sv[4 * k4 + 3];
        }
        size_t o = ((size_t)(b * 64 + c) << 16) + hw;
        kout[o] = ak;
        vout[o] = av;
    }
}

// ---------- kernel 5: MFMA attention with bf16 hi/lo split (fp32-grade accuracy)
// block: 512 thr (8 waves), one 64-row q tile of one head. Wave w owns cols [w*32, w*32+32).
// LDS layout (bytes):
//   qhi @0      [64][72]  9216      qlo @9216
//   khi @18432  [256][72] 36864     klo @55296            (phase 1; end 92160)
//   redm @92160 [8][64]f  2048      reds @94208 2048
//   phi @18432  [64][264] 33792     plo @52224            (phase 2, over k)
//   vthi @96256 [256][40] 20480     vtlo @116736          (phase 3; end 137216)
//   ost @18432  [64][260]f 66560                          (epilogue, over p)
__global__ __launch_bounds__(512)
void attn_mfma_kernel(float* __restrict__ qo, const float* __restrict__ kbuf,
                      const float* __restrict__ vbuf) {
    __shared__ char sm[137216];
    unsigned short* qhi = (unsigned short*)(sm);
    unsigned short* qlo = (unsigned short*)(sm + 9216);
    unsigned short* khi = (unsigned short*)(sm + 18432);
    unsigned short* klo = (unsigned short*)(sm + 55296);
    float* redm = (float*)(sm + 92160);
    float* reds = (float*)(sm + 94208);
    unsigned short* phi = (unsigned short*)(sm + 18432);
    unsigned short* plo = (unsigned short*)(sm + 52224);
    unsigned short* vthi = (unsigned short*)(sm + 96256);
    unsigned short* vtlo = (unsigned short*)(sm + 116736);
    float* ost = (float*)(sm + 18432);

    int t = threadIdx.x;
    int lane = t & 63, w = t >> 6;
    int lrow = lane & 15, lgrp = lane >> 4;
    int wc = w * 32;

    int bid = blockIdx.x;
    int x = bid & 7, r = bid >> 3;          // XCD grouping: 4 row-tiles of a head adjacent
    int head = x * 64 + (r >> 2), rt = r & 3;
    float* qg = qo + (((size_t)head) << 16) + rt * 64 * 256;
    const float* kg = kbuf + (((size_t)head) << 16);
    const float* vg = vbuf + (((size_t)head) << 16);

    f32x4 acc[4][2];
#pragma unroll
    for (int mi = 0; mi < 4; ++mi)
#pragma unroll
        for (int nj = 0; nj < 2; ++nj) acc[mi][nj] = (f32x4){0.f, 0.f, 0.f, 0.f};

    // ---- phase 1: S = q k^T over 4 d-chunks of 64
    for (int dc = 0; dc < 4; ++dc) {
        __syncthreads();
        {   // stage q tile 64x64 -> hi/lo
            int row = t >> 3, cb = (t & 7) * 8;
#pragma unroll
            for (int h2 = 0; h2 < 2; ++h2) {
                float4 v = *(const float4*)(qg + row * 256 + dc * 64 + cb + h2 * 4);
                unsigned short h0 = bf16_rn(v.x), h1 = bf16_rn(v.y), h2s = bf16_rn(v.z), h3 = bf16_rn(v.w);
                unsigned short l0 = bf16_rn(v.x - bf16_f(h0)), l1 = bf16_rn(v.y - bf16_f(h1));
                unsigned short l2 = bf16_rn(v.z - bf16_f(h2s)), l3 = bf16_rn(v.w - bf16_f(h3));
                ushort4 hv = {h0, h1, h2s, h3}, lv = {l0, l1, l2, l3};
                *(ushort4*)&qhi[row * 72 + cb + h2 * 4] = hv;
                *(ushort4*)&qlo[row * 72 + cb + h2 * 4] = lv;
            }
        }
        {   // stage k tile 256x64 -> hi/lo
#pragma unroll
            for (int it = 0; it < 4; ++it) {
                int row = (t >> 3) + it * 64, cb = (t & 7) * 8;
#pragma unroll
                for (int h2 = 0; h2 < 2; ++h2) {
                    float4 v = *(const float4*)(kg + row * 256 + dc * 64 + cb + h2 * 4);
                    unsigned short h0 = bf16_rn(v.x), h1 = bf16_rn(v.y), h2s = bf16_rn(v.z), h3 = bf16_rn(v.w);
                    unsigned short l0 = bf16_rn(v.x - bf16_f(h0)), l1 = bf16_rn(v.y - bf16_f(h1));
                    unsigned short l2 = bf16_rn(v.z - bf16_f(h2s)), l3 = bf16_rn(v.w - bf16_f(h3));
                    ushort4 hv = {h0, h1, h2s, h3}, lv = {l0, l1, l2, l3};
                    *(ushort4*)&khi[row * 72 + cb + h2 * 4] = hv;
                    *(ushort4*)&klo[row * 72 + cb + h2 * 4] = lv;
                }
            }
        }
        __syncthreads();
#pragma unroll
        for (int kk = 0; kk < 2; ++kk) {
            int k0 = kk * 32 + lgrp * 8;
            short8b ah[4], al[4], bh[2], bl[2];
#pragma unroll
            for (int mi = 0; mi < 4; ++mi) {
                ah[mi] = *(short8b*)&qhi[(mi * 16 + lrow) * 72 + k0];
                al[mi] = *(short8b*)&qlo[(mi * 16 + lrow) * 72 + k0];
            }
#pragma unroll
            for (int nj = 0; nj < 2; ++nj) {
                bh[nj] = *(short8b*)&khi[(wc + nj * 16 + lrow) * 72 + k0];
                bl[nj] = *(short8b*)&klo[(wc + nj * 16 + lrow) * 72 + k0];
            }
#pragma unroll
            for (int mi = 0; mi < 4; ++mi)
#pragma unroll
                for (int nj = 0; nj < 2; ++nj) {
                    acc[mi][nj] = MFMA16(ah[mi], bh[nj], acc[mi][nj], 0, 0, 0);
                    acc[mi][nj] = MFMA16(ah[mi], bl[nj], acc[mi][nj], 0, 0, 0);
                    acc[mi][nj] = MFMA16(al[mi], bh[nj], acc[mi][nj], 0, 0, 0);
                }
        }
    }

    // ---- phase 2: softmax (rows = i, reduce across 256 cols = 16 lanes x 2 nj x 8 waves)
#pragma unroll
    for (int mi = 0; mi < 4; ++mi)
#pragma unroll
        for (int nj = 0; nj < 2; ++nj) acc[mi][nj] *= 0.125f;

    float mx[4][4];
#pragma unroll
    for (int mi = 0; mi < 4; ++mi)
#pragma unroll
        for (int rr = 0; rr < 4; ++rr) {
            float m = fmaxf(acc[mi][0][rr], acc[mi][1][rr]);
            m = fmaxf(m, __shfl_xor(m, 1));
            m = fmaxf(m, __shfl_xor(m, 2));
            m = fmaxf(m, __shfl_xor(m, 4));
            m = fmaxf(m, __shfl_xor(m, 8));
            mx[mi][rr] = m;
        }
    if (lrow == 0) {
#pragma unroll
        for (int mi = 0; mi < 4; ++mi)
#pragma unroll
            for (int rr = 0; rr < 4; ++rr)
                redm[w * 64 + mi * 16 + lgrp * 4 + rr] = mx[mi][rr];
    }
    __syncthreads();   // also guarantees all khi/klo reads done before phi overwrite
    float invl[4][4];
#pragma unroll
    for (int mi = 0; mi < 4; ++mi)
#pragma unroll
        for (int rr = 0; rr < 4; ++rr) {
            int row = mi * 16 + lgrp * 4 + rr;
            float m = redm[row];
#pragma unroll
            for (int ww = 1; ww < 8; ++ww) m = fmaxf(m, redm[ww * 64 + row]);
            float p0 = __expf(acc[mi][0][rr] - m);
            float p1 = __expf(acc[mi][1][rr] - m);
            unsigned short h0 = bf16_rn(p0), h1 = bf16_rn(p1);
            phi[row * 264 + wc + lrow] = h0;
            phi[row * 264 + wc + 16 + lrow] = h1;
            plo[row * 264 + wc + lrow] = bf16_rn(p0 - bf16_f(h0));
            plo[row * 264 + wc + 16 + lrow] = bf16_rn(p1 - bf16_f(h1));
            float ls = p0 + p1;
            ls += __shfl_xor(ls, 1);
            ls += __shfl_xor(ls, 2);
            ls += __shfl_xor(ls, 4);
            ls += __shfl_xor(ls, 8);
            invl[mi][rr] = ls;   // wave-local sum for now
            if (lrow == 0) reds[w * 64 + row] = ls;
        }
    __syncthreads();   // reds ready; phi/plo fully written
#pragma unroll
    for (int mi = 0; mi < 4; ++mi)
#pragma unroll
        for (int rr = 0; rr < 4; ++rr) {
            int row = mi * 16 + lgrp * 4 + rr;
            float l = 0.f;
#pragma unroll
            for (int ww = 0; ww < 8; ++ww) l += reds[ww * 64 + row];
            invl[mi][rr] = 1.f / l;
        }

    // ---- phase 3: O = P V over 8 j-chunks of 32
#pragma unroll
    for (int mi = 0; mi < 4; ++mi)
#pragma unroll
        for (int nd = 0; nd < 2; ++nd) acc[mi][nd] = (f32x4){0.f, 0.f, 0.f, 0.f};

    for (int jc = 0; jc < 8; ++jc) {
        {   // stage V transposed: vthi[dcol][j], j in chunk of 32
            int j = t & 31, du = t >> 5;
#pragma unroll
            for (int it = 0; it < 4; ++it) {
                float4 v = *(const float4*)(vg + (size_t)(jc * 32 + j) * 256 + du * 16 + it * 4);
                float vals[4] = {v.x, v.y, v.z, v.w};
#pragma unroll
                for (int u = 0; u < 4; ++u) {
                    int dcol = du * 16 + it * 4 + u;
                    unsigned short hh = bf16_rn(vals[u]);
                    vthi[dcol * 40 + j] = hh;
                    vtlo[dcol * 40 + j] = bf16_rn(vals[u] - bf16_f(hh));
                }
            }
        }
        __syncthreads();
        int j0 = lgrp * 8;
        short8b pa[4], pb[4], vh[2], vl[2];
#pragma unroll
        for (int mi = 0; mi < 4; ++mi) {
            pa[mi] = *(short8b*)&phi[(mi * 16 + lrow) * 264 + jc * 32 + j0];
            pb[mi] = *(short8b*)&plo[(mi * 16 + lrow) * 264 + jc * 32 + j0];
        }
#pragma unroll
        for (int nd = 0; nd < 2; ++nd) {
            vh[nd] = *(short8b*)&vthi[(wc + nd * 16 + lrow) * 40 + j0];
            vl[nd] = *(short8b*)&vtlo[(wc + nd * 16 + lrow) * 40 + j0];
        }
#pragma unroll
        for (int mi = 0; mi < 4; ++mi)
#pragma unroll
            for (int nd = 0; nd < 2; ++nd) {
                acc[mi][nd] = MFMA16(pa[mi], vh[nd], acc[mi][nd], 0, 0, 0);
                acc[mi][nd] = MFMA16(pa[mi], vl[nd], acc[mi][nd], 0, 0, 0);
                acc[mi][nd] = MFMA16(pb[mi], vh[nd], acc[mi][nd], 0, 0, 0);
            }
        __syncthreads();
    }

    // ---- epilogue: scale by 1/l, stage in LDS, coalesced store over q
#pragma unroll
    for (int mi = 0; mi < 4; ++mi)
#pragma unroll
        for (int nd = 0; nd < 2; ++nd)
#pragma unroll
            for (int rr = 0; rr < 4; ++rr)
                ost[(mi * 16 + lgrp * 4 + rr) * 260 + wc + nd * 16 + lrow] =
                    acc[mi][nd][rr] * invl[mi][rr];
    __syncthreads();
#pragma unroll
    for (int it = 0; it < 8; ++it) {
        int id = it * 512 + t;
        int row = id >> 6, col4 = (id & 63) * 4;
        float4 vv = *(float4*)&ost[row * 260 + col4];
        *(float4*)(qg + row * 256 + col4) = vv;
    }
}

extern "C" void kernel_launch(void* const* d_in, const int* in_sizes, int n_in,
                              void* d_out, int out_size, void* d_ws, size_t ws_size,
                              hipStream_t stream) {
    const float* x     = (const float*)d_in[0];
    const float* Wq    = (const float*)d_in[1];
    const float* bq    = (const float*)d_in[2];
    const float* Wk    = (const float*)d_in[3];
    const float* bk    = (const float*)d_in[4];
    const float* Wv    = (const float*)d_in[5];
    const float* bv    = (const float*)d_in[6];
    const float* Woff1 = (const float*)d_in[7];
    const float* boff1 = (const float*)d_in[8];
    const float* Woff2 = (const float*)d_in[9];
    const float* rpb   = (const float*)d_in[10];
    const float* Wout  = (const float*)d_in[11];
    const float* bout  = (const float*)d_in[12];
    float* out = (float*)d_out;

    float* ws     = (float*)d_ws;
    float* qbuf   = ws;
    float* kbuf   = qbuf + (size_t)NPIX * 64;
    float* vbuf   = kbuf + (size_t)NPIX * 64;
    float* coords = vbuf + (size_t)NPIX * 64;
    float* wcomb  = coords + (size_t)NPIX * 2;
    float* bcomb  = wcomb + 3200;

    build_wcomb_kernel<<<13, 256, 0, stream>>>(Woff1, boff1, Woff2, wcomb, bcomb);
    conv1x1_kernel<1><<<NPIX / 64, 256, 0, stream>>>(x, Wq, bq, qbuf);
    offset_kernel<<<dim3(16, 16, 8), 256, 0, stream>>>(qbuf, wcomb, bcomb, (float2*)coords);
    sample_kv_kernel<<<NPIX / 64, 256, 0, stream>>>(x, (const float2*)coords, Wk, bk, Wv, bv,
                                                    rpb, kbuf, vbuf);
    attn_mfma_kernel<<<2048, 512, 0, stream>>>(qbuf, kbuf, vbuf);
    conv1x1_kernel<0><<<NPIX / 64, 256, 0, stream>>>(qbuf, Wout, bout, out);
}

// Round 3
// 981.724 us; speedup vs baseline: 3.4675x; 1.3816x over previous
//
#include <hip/hip_runtime.h>
#include <math.h>

#define HWB 65536
#define NPIX 524288   // 8*256*256

typedef __attribute__((ext_vector_type(8))) short short8b;
typedef __attribute__((ext_vector_type(4))) float f32x4;
#define MFMA16 __builtin_amdgcn_mfma_f32_16x16x32_bf16

__device__ inline unsigned short bf16_rn(float x) {
    unsigned u = __float_as_uint(x);
    unsigned r = (u + 0x7FFFu + ((u >> 16) & 1u)) >> 16;
    return (unsigned short)r;
}
__device__ inline float bf16_f(unsigned short h) {
    return __uint_as_float(((unsigned)h) << 16);
}

// ---------- kernel 1a: collapse offset head: Wcomb[p][cin][tap] = sum_c Woff2[p,c]*Woff1[c,cin,tap]
__global__ void build_wcomb_kernel(const float* __restrict__ Woff1,
                                   const float* __restrict__ boff1,
                                   const float* __restrict__ Woff2,
                                   float* __restrict__ wcomb,
                                   float* __restrict__ bcomb) {
    int idx = blockIdx.x * 256 + threadIdx.x;
    if (idx < 2 * 64 * 25) {
        int p = idx / 1600;
        int rest = idx - p * 1600;
        float s = 0.f;
        for (int cm = 0; cm < 64; ++cm)
            s += Woff2[p * 64 + cm] * Woff1[cm * 1600 + rest];
        wcomb[idx] = s;
    }
    if (idx < 2) {
        float s = 0.f;
        for (int cm = 0; cm < 64; ++cm) s += Woff2[idx * 64 + cm] * boff1[cm];
        bcomb[idx] = s;
    }
}

// ---------- kernel 1b: Wcat[128][64] = [Wq ; Wproj@Wq ; 0], bcat[128] = [bq ; Wproj@bq ; 0]
// Wproj[ch][cin] = wcomb[p][cin][tap], ch = p*25+tap
__global__ void build_wcat_kernel(const float* __restrict__ Wq, const float* __restrict__ bq,
                                  const float* __restrict__ wcomb,
                                  float* __restrict__ wcat, float* __restrict__ bcat) {
    int idx = blockIdx.x * 256 + threadIdx.x;
    if (idx < 8192) {
        int r = idx >> 6, c = idx & 63;
        float v = 0.f;
        if (r < 64) v = Wq[r * 64 + c];
        else if (r < 114) {
            int ch = r - 64, p = ch / 25, tap = ch % 25;
            for (int cin = 0; cin < 64; ++cin)
                v += wcomb[p * 1600 + cin * 25 + tap] * Wq[cin * 64 + c];
        }
        wcat[idx] = v;
    }
    if (idx >= 8192 && idx < 8192 + 128) {
        int r = idx - 8192;
        float v = 0.f;
        if (r < 64) v = bq[r];
        else if (r < 114) {
            int ch = r - 64, p = ch / 25, tap = ch % 25;
            for (int cin = 0; cin < 64; ++cin)
                v += wcomb[p * 1600 + cin * 25 + tap] * bq[cin];
        }
        bcat[r] = v;
    }
}

// ---------- kernel 2: fused q + proj conv (128-channel 1x1 conv on x)
// q channels 0..63 -> planar qout[(b*64+c)<<16 + hw]; channels 64..113 -> proj[(b*50+ch)<<16 + hw]
__global__ __launch_bounds__(256)
void convqp_kernel(const float* __restrict__ in, const float* __restrict__ wcat,
                   const float* __restrict__ bcat, float* __restrict__ qout,
                   float* __restrict__ projout) {
    __shared__ float Wl[8192];
    __shared__ float bl[128];
    __shared__ float xT[64][64];
    int t = threadIdx.x;
    for (int i = t; i < 8192; i += 256) Wl[i] = wcat[i];
    if (t < 128) bl[t] = bcat[t];
    int p = t & 63, j = t >> 6;
    int pix = blockIdx.x * 64 + p;
    const float4* src = (const float4*)(in + (size_t)pix * 64 + j * 16);
#pragma unroll
    for (int q4 = 0; q4 < 4; ++q4) {
        float4 v = src[q4];
        int kk = j * 16 + q4 * 4;
        xT[kk][p] = v.x; xT[kk + 1][p] = v.y; xT[kk + 2][p] = v.z; xT[kk + 3][p] = v.w;
    }
    __syncthreads();
    float sv[64];
#pragma unroll
    for (int kk = 0; kk < 64; ++kk) sv[kk] = xT[kk][p];
    int b = pix >> 16, hw = pix & 65535;
#pragma unroll
    for (int u = 0; u < 32; ++u) {
        int c = j * 32 + u;
        float a = bl[c];
        const float4* wrow = (const float4*)(Wl + c * 64);
#pragma unroll
        for (int k4 = 0; k4 < 16; ++k4) {
            float4 w = wrow[k4];
            a += w.x * sv[4 * k4] + w.y * sv[4 * k4 + 1] + w.z * sv[4 * k4 + 2] + w.w * sv[4 * k4 + 3];
        }
        if (c < 64) qout[((size_t)(b * 64 + c) << 16) + hw] = a;
        else if (c < 114) projout[((size_t)(b * 50 + (c - 64)) << 16) + hw] = a;
    }
}

// ---------- kernel 3: offset via 25-tap shift-add over proj planes, -> sample coords
__global__ __launch_bounds__(256)
void offset_gather_kernel(const float* __restrict__ proj, const float* __restrict__ bcomb,
                          float2* __restrict__ coords) {
    int x = threadIdx.x, y = blockIdx.x, b = blockIdx.y;
    const float* pb = proj + (((size_t)b * 50) << 16);
    float a0 = bcomb[0], a1 = bcomb[1];
#pragma unroll
    for (int ky = 0; ky < 5; ++ky) {
        int yy = y + ky - 2;
        if (yy < 0 || yy >= 256) continue;
#pragma unroll
        for (int kx = 0; kx < 5; ++kx) {
            int xx = x + kx - 2;
            if (xx < 0 || xx >= 256) continue;
            int tap = ky * 5 + kx;
            size_t off = (size_t)yy * 256 + xx;
            a0 += pb[((size_t)tap << 16) + off];
            a1 += pb[((size_t)(25 + tap) << 16) + off];
        }
    }
    float ox = tanhf(a0) * 5.f, oy = tanhf(a1) * 5.f;
    float vgx = (float)x + ox, vgy = (float)y + oy;
    float ix = vgx * (256.f / 255.f) - 0.5f;
    float iy = vgy * (256.f / 255.f) - 0.5f;
    coords[(((size_t)b) << 16) + y * 256 + x] = make_float2(ix, iy);
}

// ---------- kernel 4: bilinear sample + k/v 1x1 convs + rpb
__global__ __launch_bounds__(256)
void sample_kv_kernel(const float* __restrict__ x, const float2* __restrict__ coords,
                      const float* __restrict__ Wk, const float* __restrict__ bk,
                      const float* __restrict__ Wv, const float* __restrict__ bv,
                      const float* __restrict__ rpb,
                      float* __restrict__ kout, float* __restrict__ vout) {
    __shared__ float Wkl[4096], Wvl[4096];
    __shared__ float sT[64][64];
    int t = threadIdx.x;
    for (int i = t; i < 4096; i += 256) { Wkl[i] = Wk[i]; Wvl[i] = Wv[i]; }
    int p = t & 63, j = t >> 6;
    int pix = blockIdx.x * 64 + p;
    int b = pix >> 16, hw = pix & 65535, h = hw >> 8;
    float2 cc = coords[pix];
    float ix0f = floorf(cc.x), iy0f = floorf(cc.y);
    float wx1 = cc.x - ix0f, wy1 = cc.y - iy0f;
    float wx0 = 1.f - wx1, wy0 = 1.f - wy1;
    int ix0 = (int)ix0f, iy0 = (int)iy0f;
    float s[16];
#pragma unroll
    for (int u = 0; u < 16; ++u) s[u] = 0.f;
    const float* xb = x + (((size_t)b) << 16) * 64 + j * 16;
    int cxs[4] = {ix0, ix0 + 1, ix0, ix0 + 1};
    int cys[4] = {iy0, iy0, iy0 + 1, iy0 + 1};
    float ws4[4] = {wx0 * wy0, wx1 * wy0, wx0 * wy1, wx1 * wy1};
#pragma unroll
    for (int cr = 0; cr < 4; ++cr) {
        int cx = cxs[cr], cy = cys[cr];
        if (cx >= 0 && cx < 256 && cy >= 0 && cy < 256) {
            float wgt = ws4[cr];
            const float4* sp = (const float4*)(xb + ((size_t)(cy * 256 + cx) << 6));
#pragma unroll
            for (int q4 = 0; q4 < 4; ++q4) {
                float4 v = sp[q4];
                s[4 * q4] += wgt * v.x; s[4 * q4 + 1] += wgt * v.y;
                s[4 * q4 + 2] += wgt * v.z; s[4 * q4 + 3] += wgt * v.w;
            }
        }
    }
#pragma unroll
    for (int u = 0; u < 16; ++u) sT[j * 16 + u][p] = s[u];
    __syncthreads();
    float sv[64];
#pragma unroll
    for (int kk = 0; kk < 64; ++kk) sv[kk] = sT[kk][p];
#pragma unroll
    for (int u = 0; u < 16; ++u) {
        int c = j * 16 + u;
        float ak = bk[c];
        float av = bv[c] + rpb[c * 256 + h];
        const float4* wkr = (const float4*)(Wkl + c * 64);
        const float4* wvr = (const float4*)(Wvl + c * 64);
#pragma unroll
        for (int k4 = 0; k4 < 16; ++k4) {
            float4 w1 = wkr[k4], w2 = wvr[k4];
            ak += w1.x * sv[4 * k4] + w1.y * sv[4 * k4 + 1] + w1.z * sv[4 * k4 + 2] + w1.w * sv[4 * k4 + 3];
            av += w2.x * sv[4 * k4] + w2.y * sv[4 * k4 + 1] + w2.z * sv[4 * k4 + 2] + w2.w * sv[4 * k4 + 3];
        }
        size_t o = ((size_t)(b * 64 + c) << 16) + hw;
        kout[o] = ak;
        vout[o] = av;
    }
}

// ---------- kernel 5: MFMA attention with bf16 hi/lo split (fp32-grade accuracy)
__global__ __launch_bounds__(512)
void attn_mfma_kernel(float* __restrict__ qo, const float* __restrict__ kbuf,
                      const float* __restrict__ vbuf) {
    __shared__ char sm[137216];
    unsigned short* qhi = (unsigned short*)(sm);
    unsigned short* qlo = (unsigned short*)(sm + 9216);
    unsigned short* khi = (unsigned short*)(sm + 18432);
    unsigned short* klo = (unsigned short*)(sm + 55296);
    float* redm = (float*)(sm + 92160);
    float* reds = (float*)(sm + 94208);
    unsigned short* phi = (unsigned short*)(sm + 18432);
    unsigned short* plo = (unsigned short*)(sm + 52224);
    unsigned short* vthi = (unsigned short*)(sm + 96256);
    unsigned short* vtlo = (unsigned short*)(sm + 116736);
    float* ost = (float*)(sm + 18432);

    int t = threadIdx.x;
    int lane = t & 63, w = t >> 6;
    int lrow = lane & 15, lgrp = lane >> 4;
    int wc = w * 32;

    int bid = blockIdx.x;
    int x = bid & 7, r = bid >> 3;
    int head = x * 64 + (r >> 2), rt = r & 3;
    float* qg = qo + (((size_t)head) << 16) + rt * 64 * 256;
    const float* kg = kbuf + (((size_t)head) << 16);
    const float* vg = vbuf + (((size_t)head) << 16);

    f32x4 acc[4][2];
#pragma unroll
    for (int mi = 0; mi < 4; ++mi)
#pragma unroll
        for (int nj = 0; nj < 2; ++nj) acc[mi][nj] = (f32x4){0.f, 0.f, 0.f, 0.f};

    for (int dc = 0; dc < 4; ++dc) {
        __syncthreads();
        {
            int row = t >> 3, cb = (t & 7) * 8;
#pragma unroll
            for (int h2 = 0; h2 < 2; ++h2) {
                float4 v = *(const float4*)(qg + row * 256 + dc * 64 + cb + h2 * 4);
                unsigned short h0 = bf16_rn(v.x), h1 = bf16_rn(v.y), h2s = bf16_rn(v.z), h3 = bf16_rn(v.w);
                unsigned short l0 = bf16_rn(v.x - bf16_f(h0)), l1 = bf16_rn(v.y - bf16_f(h1));
                unsigned short l2 = bf16_rn(v.z - bf16_f(h2s)), l3 = bf16_rn(v.w - bf16_f(h3));
                ushort4 hv = {h0, h1, h2s, h3}, lv = {l0, l1, l2, l3};
                *(ushort4*)&qhi[row * 72 + cb + h2 * 4] = hv;
                *(ushort4*)&qlo[row * 72 + cb + h2 * 4] = lv;
            }
        }
        {
#pragma unroll
            for (int it = 0; it < 4; ++it) {
                int row = (t >> 3) + it * 64, cb = (t & 7) * 8;
#pragma unroll
                for (int h2 = 0; h2 < 2; ++h2) {
                    float4 v = *(const float4*)(kg + row * 256 + dc * 64 + cb + h2 * 4);
                    unsigned short h0 = bf16_rn(v.x), h1 = bf16_rn(v.y), h2s = bf16_rn(v.z), h3 = bf16_rn(v.w);
                    unsigned short l0 = bf16_rn(v.x - bf16_f(h0)), l1 = bf16_rn(v.y - bf16_f(h1));
                    unsigned short l2 = bf16_rn(v.z - bf16_f(h2s)), l3 = bf16_rn(v.w - bf16_f(h3));
                    ushort4 hv = {h0, h1, h2s, h3}, lv = {l0, l1, l2, l3};
                    *(ushort4*)&khi[row * 72 + cb + h2 * 4] = hv;
                    *(ushort4*)&klo[row * 72 + cb + h2 * 4] = lv;
                }
            }
        }
        __syncthreads();
#pragma unroll
        for (int kk = 0; kk < 2; ++kk) {
            int k0 = kk * 32 + lgrp * 8;
            short8b ah[4], al[4], bh[2], bl[2];
#pragma unroll
            for (int mi = 0; mi < 4; ++mi) {
                ah[mi] = *(short8b*)&qhi[(mi * 16 + lrow) * 72 + k0];
                al[mi] = *(short8b*)&qlo[(mi * 16 + lrow) * 72 + k0];
            }
#pragma unroll
            for (int nj = 0; nj < 2; ++nj) {
                bh[nj] = *(short8b*)&khi[(wc + nj * 16 + lrow) * 72 + k0];
                bl[nj] = *(short8b*)&klo[(wc + nj * 16 + lrow) * 72 + k0];
            }
#pragma unroll
            for (int mi = 0; mi < 4; ++mi)
#pragma unroll
                for (int nj = 0; nj < 2; ++nj) {
                    acc[mi][nj] = MFMA16(ah[mi], bh[nj], acc[mi][nj], 0, 0, 0);
                    acc[mi][nj] = MFMA16(ah[mi], bl[nj], acc[mi][nj], 0, 0, 0);
                    acc[mi][nj] = MFMA16(al[mi], bh[nj], acc[mi][nj], 0, 0, 0);
                }
        }
    }

#pragma unroll
    for (int mi = 0; mi < 4; ++mi)
#pragma unroll
        for (int nj = 0; nj < 2; ++nj) acc[mi][nj] *= 0.125f;

    float mx[4][4];
#pragma unroll
    for (int mi = 0; mi < 4; ++mi)
#pragma unroll
        for (int rr = 0; rr < 4; ++rr) {
            float m = fmaxf(acc[mi][0][rr], acc[mi][1][rr]);
            m = fmaxf(m, __shfl_xor(m, 1));
            m = fmaxf(m, __shfl_xor(m, 2));
            m = fmaxf(m, __shfl_xor(m, 4));
            m = fmaxf(m, __shfl_xor(m, 8));
            mx[mi][rr] = m;
        }
    if (lrow == 0) {
#pragma unroll
        for (int mi = 0; mi < 4; ++mi)
#pragma unroll
            for (int rr = 0; rr < 4; ++rr)
                redm[w * 64 + mi * 16 + lgrp * 4 + rr] = mx[mi][rr];
    }
    __syncthreads();
    float invl[4][4];
#pragma unroll
    for (int mi = 0; mi < 4; ++mi)
#pragma unroll
        for (int rr = 0; rr < 4; ++rr) {
            int row = mi * 16 + lgrp * 4 + rr;
            float m = redm[row];
#pragma unroll
            for (int ww = 1; ww < 8; ++ww) m = fmaxf(m, redm[ww * 64 + row]);
            float p0 = __expf(acc[mi][0][rr] - m);
            float p1 = __expf(acc[mi][1][rr] - m);
            unsigned short h0 = bf16_rn(p0), h1 = bf16_rn(p1);
            phi[row * 264 + wc + lrow] = h0;
            phi[row * 264 + wc + 16 + lrow] = h1;
            plo[row * 264 + wc + lrow] = bf16_rn(p0 - bf16_f(h0));
            plo[row * 264 + wc + 16 + lrow] = bf16_rn(p1 - bf16_f(h1));
            float ls = p0 + p1;
            ls += __shfl_xor(ls, 1);
            ls += __shfl_xor(ls, 2);
            ls += __shfl_xor(ls, 4);
            ls += __shfl_xor(ls, 8);
            if (lrow == 0) reds[w * 64 + row] = ls;
        }
    __syncthreads();
#pragma unroll
    for (int mi = 0; mi < 4; ++mi)
#pragma unroll
        for (int rr = 0; rr < 4; ++rr) {
            int row = mi * 16 + lgrp * 4 + rr;
            float l = 0.f;
#pragma unroll
            for (int ww = 0; ww < 8; ++ww) l += reds[ww * 64 + row];
            invl[mi][rr] = 1.f / l;
        }

#pragma unroll
    for (int mi = 0; mi < 4; ++mi)
#pragma unroll
        for (int nd = 0; nd < 2; ++nd) acc[mi][nd] = (f32x4){0.f, 0.f, 0.f, 0.f};

    for (int jc = 0; jc < 8; ++jc) {
        {
            int j = t & 31, du = t >> 5;
#pragma unroll
            for (int it = 0; it < 4; ++it) {
                float4 v = *(const float4*)(vg + (size_t)(jc * 32 + j) * 256 + du * 16 + it * 4);
                float vals[4] = {v.x, v.y, v.z, v.w};
#pragma unroll
                for (int u = 0; u < 4; ++u) {
                    int dcol = du * 16 + it * 4 + u;
                    unsigned short hh = bf16_rn(vals[u]);
                    vthi[dcol * 40 + j] = hh;
                    vtlo[dcol * 40 + j] = bf16_rn(vals[u] - bf16_f(hh));
                }
            }
        }
        __syncthreads();
        int j0 = lgrp * 8;
        short8b pa[4], pb[4], vh[2], vl[2];
#pragma unroll
        for (int mi = 0; mi < 4; ++mi) {
            pa[mi] = *(short8b*)&phi[(mi * 16 + lrow) * 264 + jc * 32 + j0];
            pb[mi] = *(short8b*)&plo[(mi * 16 + lrow) * 264 + jc * 32 + j0];
        }
#pragma unroll
        for (int nd = 0; nd < 2; ++nd) {
            vh[nd] = *(short8b*)&vthi[(wc + nd * 16 + lrow) * 40 + j0];
            vl[nd] = *(short8b*)&vtlo[(wc + nd * 16 + lrow) * 40 + j0];
        }
#pragma unroll
        for (int mi = 0; mi < 4; ++mi)
#pragma unroll
            for (int nd = 0; nd < 2; ++nd) {
                acc[mi][nd] = MFMA16(pa[mi], vh[nd], acc[mi][nd], 0, 0, 0);
                acc[mi][nd] = MFMA16(pa[mi], vl[nd], acc[mi][nd], 0, 0, 0);
                acc[mi][nd] = MFMA16(pb[mi], vh[nd], acc[mi][nd], 0, 0, 0);
            }
        __syncthreads();
    }

#pragma unroll
    for (int mi = 0; mi < 4; ++mi)
#pragma unroll
        for (int nd = 0; nd < 2; ++nd)
#pragma unroll
            for (int rr = 0; rr < 4; ++rr)
                ost[(mi * 16 + lgrp * 4 + rr) * 260 + wc + nd * 16 + lrow] =
                    acc[mi][nd][rr] * invl[mi][rr];
    __syncthreads();
#pragma unroll
    for (int it = 0; it < 8; ++it) {
        int id = it * 512 + t;
        int row = id >> 6, col4 = (id & 63) * 4;
        float4 vv = *(float4*)&ost[row * 260 + col4];
        *(float4*)(qg + row * 256 + col4) = vv;
    }
}

// ---------- kernel 6: final 1x1 conv (pixel-major input from attention out)
__global__ __launch_bounds__(256)
void convout_kernel(const float* __restrict__ in, const float* __restrict__ Wg,
                    const float* __restrict__ bias, float* __restrict__ out) {
    __shared__ float Wl[4096];
    __shared__ float xT[64][64];
    int t = threadIdx.x;
    for (int i = t; i < 4096; i += 256) Wl[i] = Wg[i];
    int p = t & 63, j = t >> 6;
    int pix = blockIdx.x * 64 + p;
    const float4* src = (const float4*)(in + (size_t)pix * 64 + j * 16);
#pragma unroll
    for (int q4 = 0; q4 < 4; ++q4) {
        float4 v = src[q4];
        int kk = j * 16 + q4 * 4;
        xT[kk][p] = v.x; xT[kk + 1][p] = v.y; xT[kk + 2][p] = v.z; xT[kk + 3][p] = v.w;
    }
    __syncthreads();
    float sv[64];
#pragma unroll
    for (int kk = 0; kk < 64; ++kk) sv[kk] = xT[kk][p];
    float acc[16];
#pragma unroll
    for (int u = 0; u < 16; ++u) {
        int c = j * 16 + u;
        float a = bias[c];
        const float4* wrow = (const float4*)(Wl + c * 64);
#pragma unroll
        for (int k4 = 0; k4 < 16; ++k4) {
            float4 w = wrow[k4];
            a += w.x * sv[4 * k4] + w.y * sv[4 * k4 + 1] + w.z * sv[4 * k4 + 2] + w.w * sv[4 * k4 + 3];
        }
        acc[u] = a;
    }
#pragma unroll
    for (int u = 0; u < 16; ++u) out[(size_t)pix * 64 + j * 16 + u] = acc[u];
}

extern "C" void kernel_launch(void* const* d_in, const int* in_sizes, int n_in,
                              void* d_out, int out_size, void* d_ws, size_t ws_size,
                              hipStream_t stream) {
    const float* x     = (const float*)d_in[0];
    const float* Wq    = (const float*)d_in[1];
    const float* bq    = (const float*)d_in[2];
    const float* Wk    = (const float*)d_in[3];
    const float* bk    = (const float*)d_in[4];
    const float* Wv    = (const float*)d_in[5];
    const float* bv    = (const float*)d_in[6];
    const float* Woff1 = (const float*)d_in[7];
    const float* boff1 = (const float*)d_in[8];
    const float* Woff2 = (const float*)d_in[9];
    const float* rpb   = (const float*)d_in[10];
    const float* Wout  = (const float*)d_in[11];
    const float* bout  = (const float*)d_in[12];
    float* out = (float*)d_out;

    float* ws     = (float*)d_ws;
    float* qbuf   = ws;
    float* kbuf   = qbuf + (size_t)NPIX * 64;     // also aliased as proj (needs 400*65536 < NPIX*64)
    float* vbuf   = kbuf + (size_t)NPIX * 64;
    float* coords = vbuf + (size_t)NPIX * 64;
    float* wcomb  = coords + (size_t)NPIX * 2;
    float* bcomb  = wcomb + 3200;                 // 2
    float* wcat   = bcomb + 2;                    // 8192
    float* bcat   = wcat + 8192;                  // 128
    float* proj   = kbuf;

    build_wcomb_kernel<<<13, 256, 0, stream>>>(Woff1, boff1, Woff2, wcomb, bcomb);
    build_wcat_kernel<<<33, 256, 0, stream>>>(Wq, bq, wcomb, wcat, bcat);
    convqp_kernel<<<NPIX / 64, 256, 0, stream>>>(x, wcat, bcat, qbuf, proj);
    offset_gather_kernel<<<dim3(256, 8), 256, 0, stream>>>(proj, bcomb, (float2*)coords);
    sample_kv_kernel<<<NPIX / 64, 256, 0, stream>>>(x, (const float2*)coords, Wk, bk, Wv, bv,
                                                    rpb, kbuf, vbuf);
    attn_mfma_kernel<<<2048, 512, 0, stream>>>(qbuf, kbuf, vbuf);
    convout_kernel<<<NPIX / 64, 256, 0, stream>>>(qbuf, Wout, bout, out);
}

// Round 4
// 919.138 us; speedup vs baseline: 3.7036x; 1.0681x over previous
//
#include <hip/hip_runtime.h>
#include <math.h>

#define HWB 65536
#define NPIX 524288   // 8*256*256

typedef __attribute__((ext_vector_type(8))) short short8b;
typedef __attribute__((ext_vector_type(4))) float f32x4;
#define MFMA16 __builtin_amdgcn_mfma_f32_16x16x32_bf16

__device__ inline unsigned short bf16_rn(float x) {
    unsigned u = __float_as_uint(x);
    unsigned r = (u + 0x7FFFu + ((u >> 16) & 1u)) >> 16;
    return (unsigned short)r;
}
__device__ inline float bf16_f(unsigned short h) {
    return __uint_as_float(((unsigned)h) << 16);
}

// ---------- kernel 1a: collapse offset head: Wcomb[p][cin][tap] = sum_c Woff2[p,c]*Woff1[c,cin,tap]
__global__ void build_wcomb_kernel(const float* __restrict__ Woff1,
                                   const float* __restrict__ boff1,
                                   const float* __restrict__ Woff2,
                                   float* __restrict__ wcomb,
                                   float* __restrict__ bcomb) {
    int idx = blockIdx.x * 256 + threadIdx.x;
    if (idx < 2 * 64 * 25) {
        int p = idx / 1600;
        int rest = idx - p * 1600;
        float s = 0.f;
        for (int cm = 0; cm < 64; ++cm)
            s += Woff2[p * 64 + cm] * Woff1[cm * 1600 + rest];
        wcomb[idx] = s;
    }
    if (idx < 2) {
        float s = 0.f;
        for (int cm = 0; cm < 64; ++cm) s += Woff2[idx * 64 + cm] * boff1[cm];
        bcomb[idx] = s;
    }
}

// ---------- kernel 1b: Wcat[128][64] = [Wq ; Wproj@Wq ; 0]
__global__ void build_wcat_kernel(const float* __restrict__ Wq, const float* __restrict__ bq,
                                  const float* __restrict__ wcomb,
                                  float* __restrict__ wcat, float* __restrict__ bcat) {
    int idx = blockIdx.x * 256 + threadIdx.x;
    if (idx < 8192) {
        int r = idx >> 6, c = idx & 63;
        float v = 0.f;
        if (r < 64) v = Wq[r * 64 + c];
        else if (r < 114) {
            int ch = r - 64, p = ch / 25, tap = ch % 25;
            for (int cin = 0; cin < 64; ++cin)
                v += wcomb[p * 1600 + cin * 25 + tap] * Wq[cin * 64 + c];
        }
        wcat[idx] = v;
    }
    if (idx >= 8192 && idx < 8192 + 128) {
        int r = idx - 8192;
        float v = 0.f;
        if (r < 64) v = bq[r];
        else if (r < 114) {
            int ch = r - 64, p = ch / 25, tap = ch % 25;
            for (int cin = 0; cin < 64; ++cin)
                v += wcomb[p * 1600 + cin * 25 + tap] * bq[cin];
        }
        bcat[r] = v;
    }
}

// ---------- kernel 2: fused q + proj conv (128-channel 1x1 conv on x)
__global__ __launch_bounds__(256)
void convqp_kernel(const float* __restrict__ in, const float* __restrict__ wcat,
                   const float* __restrict__ bcat, float* __restrict__ qout,
                   float* __restrict__ projout) {
    __shared__ float Wl[8192];
    __shared__ float bl[128];
    __shared__ float xT[64][64];
    int t = threadIdx.x;
    for (int i = t; i < 8192; i += 256) Wl[i] = wcat[i];
    if (t < 128) bl[t] = bcat[t];
    int p = t & 63, j = t >> 6;
    int pix = blockIdx.x * 64 + p;
    const float4* src = (const float4*)(in + (size_t)pix * 64 + j * 16);
#pragma unroll
    for (int q4 = 0; q4 < 4; ++q4) {
        float4 v = src[q4];
        int kk = j * 16 + q4 * 4;
        xT[kk][p] = v.x; xT[kk + 1][p] = v.y; xT[kk + 2][p] = v.z; xT[kk + 3][p] = v.w;
    }
    __syncthreads();
    float sv[64];
#pragma unroll
    for (int kk = 0; kk < 64; ++kk) sv[kk] = xT[kk][p];
    int b = pix >> 16, hw = pix & 65535;
#pragma unroll
    for (int u = 0; u < 32; ++u) {
        int c = j * 32 + u;
        float a = bl[c];
        const float4* wrow = (const float4*)(Wl + c * 64);
#pragma unroll
        for (int k4 = 0; k4 < 16; ++k4) {
            float4 w = wrow[k4];
            a += w.x * sv[4 * k4] + w.y * sv[4 * k4 + 1] + w.z * sv[4 * k4 + 2] + w.w * sv[4 * k4 + 3];
        }
        if (c < 64) qout[((size_t)(b * 64 + c) << 16) + hw] = a;
        else if (c < 114) projout[((size_t)(b * 50 + (c - 64)) << 16) + hw] = a;
    }
}

// ---------- kernel 3: offset via 25-tap shift-add over proj planes -> sample coords
__global__ __launch_bounds__(256)
void offset_gather_kernel(const float* __restrict__ proj, const float* __restrict__ bcomb,
                          float2* __restrict__ coords) {
    int x = threadIdx.x, y = blockIdx.x, b = blockIdx.y;
    const float* pb = proj + (((size_t)b * 50) << 16);
    float a0 = bcomb[0], a1 = bcomb[1];
#pragma unroll
    for (int ky = 0; ky < 5; ++ky) {
        int yy = y + ky - 2;
        if (yy < 0 || yy >= 256) continue;
#pragma unroll
        for (int kx = 0; kx < 5; ++kx) {
            int xx = x + kx - 2;
            if (xx < 0 || xx >= 256) continue;
            int tap = ky * 5 + kx;
            size_t off = (size_t)yy * 256 + xx;
            a0 += pb[((size_t)tap << 16) + off];
            a1 += pb[((size_t)(25 + tap) << 16) + off];
        }
    }
    float ox = tanhf(a0) * 5.f, oy = tanhf(a1) * 5.f;
    float vgx = (float)x + ox, vgy = (float)y + oy;
    float ix = vgx * (256.f / 255.f) - 0.5f;
    float iy = vgy * (256.f / 255.f) - 0.5f;
    coords[(((size_t)b) << 16) + y * 256 + x] = make_float2(ix, iy);
}

// ---------- kernel 4: bilinear sample + k/v 1x1 convs + rpb, emit bf16 hi/lo planes
__global__ __launch_bounds__(256)
void sample_kv_kernel(const float* __restrict__ x, const float2* __restrict__ coords,
                      const float* __restrict__ Wk, const float* __restrict__ bk,
                      const float* __restrict__ Wv, const float* __restrict__ bv,
                      const float* __restrict__ rpb,
                      unsigned short* __restrict__ khi, unsigned short* __restrict__ klo,
                      unsigned short* __restrict__ vhi, unsigned short* __restrict__ vlo) {
    __shared__ float Wkl[4096], Wvl[4096];
    __shared__ float sT[64][64];
    int t = threadIdx.x;
    for (int i = t; i < 4096; i += 256) { Wkl[i] = Wk[i]; Wvl[i] = Wv[i]; }
    int p = t & 63, j = t >> 6;
    int pix = blockIdx.x * 64 + p;
    int b = pix >> 16, hw = pix & 65535, h = hw >> 8;
    float2 cc = coords[pix];
    float ix0f = floorf(cc.x), iy0f = floorf(cc.y);
    float wx1 = cc.x - ix0f, wy1 = cc.y - iy0f;
    float wx0 = 1.f - wx1, wy0 = 1.f - wy1;
    int ix0 = (int)ix0f, iy0 = (int)iy0f;
    float s[16];
#pragma unroll
    for (int u = 0; u < 16; ++u) s[u] = 0.f;
    const float* xb = x + (((size_t)b) << 16) * 64 + j * 16;
    int cxs[4] = {ix0, ix0 + 1, ix0, ix0 + 1};
    int cys[4] = {iy0, iy0, iy0 + 1, iy0 + 1};
    float ws4[4] = {wx0 * wy0, wx1 * wy0, wx0 * wy1, wx1 * wy1};
#pragma unroll
    for (int cr = 0; cr < 4; ++cr) {
        int cx = cxs[cr], cy = cys[cr];
        if (cx >= 0 && cx < 256 && cy >= 0 && cy < 256) {
            float wgt = ws4[cr];
            const float4* sp = (const float4*)(xb + ((size_t)(cy * 256 + cx) << 6));
#pragma unroll
            for (int q4 = 0; q4 < 4; ++q4) {
                float4 v = sp[q4];
                s[4 * q4] += wgt * v.x; s[4 * q4 + 1] += wgt * v.y;
                s[4 * q4 + 2] += wgt * v.z; s[4 * q4 + 3] += wgt * v.w;
            }
        }
    }
#pragma unroll
    for (int u = 0; u < 16; ++u) sT[j * 16 + u][p] = s[u];
    __syncthreads();
    float sv[64];
#pragma unroll
    for (int kk = 0; kk < 64; ++kk) sv[kk] = sT[kk][p];
#pragma unroll
    for (int u = 0; u < 16; ++u) {
        int c = j * 16 + u;
        float ak = bk[c];
        float av = bv[c] + rpb[c * 256 + h];
        const float4* wkr = (const float4*)(Wkl + c * 64);
        const float4* wvr = (const float4*)(Wvl + c * 64);
#pragma unroll
        for (int k4 = 0; k4 < 16; ++k4) {
            float4 w1 = wkr[k4], w2 = wvr[k4];
            ak += w1.x * sv[4 * k4] + w1.y * sv[4 * k4 + 1] + w1.z * sv[4 * k4 + 2] + w1.w * sv[4 * k4 + 3];
            av += w2.x * sv[4 * k4] + w2.y * sv[4 * k4 + 1] + w2.z * sv[4 * k4 + 2] + w2.w * sv[4 * k4 + 3];
        }
        size_t o = ((size_t)(b * 64 + c) << 16) + hw;
        unsigned short kh = bf16_rn(ak);
        unsigned short vh = bf16_rn(av);
        khi[o] = kh; klo[o] = bf16_rn(ak - bf16_f(kh));
        vhi[o] = vh; vlo[o] = bf16_rn(av - bf16_f(vh));
    }
}

// ---------- kernel 4b: in-place paired-tile transpose of v hi/lo planes ([head][j][d] -> [head][d][j])
__global__ __launch_bounds__(256)
void vtrans_kernel(unsigned short* __restrict__ vhi, unsigned short* __restrict__ vlo) {
    __shared__ unsigned short T1[64][72];
    __shared__ unsigned short T2[64][72];
    const int ti_tab[10] = {0, 0, 0, 0, 1, 1, 1, 2, 2, 3};
    const int tj_tab[10] = {0, 1, 2, 3, 1, 2, 3, 2, 3, 3};
    int head = blockIdx.x / 10, pidx = blockIdx.x - head * 10;
    int ti = ti_tab[pidx], tj = tj_tab[pidx];
    int t = threadIdx.x;
    int r = t >> 2, cs = (t & 3) * 16;
    bool diag = (ti == tj);
#pragma unroll
    for (int pl = 0; pl < 2; ++pl) {
        unsigned short* base = (pl ? vlo : vhi) + ((size_t)head << 16);
        *(short8b*)&T1[r][cs]     = *(const short8b*)(base + (size_t)(ti * 64 + r) * 256 + tj * 64 + cs);
        *(short8b*)&T1[r][cs + 8] = *(const short8b*)(base + (size_t)(ti * 64 + r) * 256 + tj * 64 + cs + 8);
        if (!diag) {
            *(short8b*)&T2[r][cs]     = *(const short8b*)(base + (size_t)(tj * 64 + r) * 256 + ti * 64 + cs);
            *(short8b*)&T2[r][cs + 8] = *(const short8b*)(base + (size_t)(tj * 64 + r) * 256 + ti * 64 + cs + 8);
        }
        __syncthreads();
        {
            short8b o0, o1;
#pragma unroll
            for (int u = 0; u < 8; ++u) { o0[u] = (short)T1[cs + u][r]; o1[u] = (short)T1[cs + 8 + u][r]; }
            *(short8b*)(base + (size_t)(tj * 64 + r) * 256 + ti * 64 + cs) = o0;
            *(short8b*)(base + (size_t)(tj * 64 + r) * 256 + ti * 64 + cs + 8) = o1;
            if (!diag) {
#pragma unroll
                for (int u = 0; u < 8; ++u) { o0[u] = (short)T2[cs + u][r]; o1[u] = (short)T2[cs + 8 + u][r]; }
                *(short8b*)(base + (size_t)(ti * 64 + r) * 256 + tj * 64 + cs) = o0;
                *(short8b*)(base + (size_t)(ti * 64 + r) * 256 + tj * 64 + cs + 8) = o1;
            }
        }
        __syncthreads();
    }
}

// ---------- kernel 5: MFMA attention; k/v fragments direct from global bf16 planes
// LDS: region A 67584B = qhi[64][264]+qlo  ->  phi/plo  ->  ost[64][260]f ; red @67584
__global__ __launch_bounds__(512, 4)
void attn_mfma_kernel(float* __restrict__ qo,
                      const unsigned short* __restrict__ khig, const unsigned short* __restrict__ klog,
                      const unsigned short* __restrict__ vthig, const unsigned short* __restrict__ vtlog) {
    __shared__ char sm[71680];
    unsigned short* qhi = (unsigned short*)sm;
    unsigned short* qlo = (unsigned short*)(sm + 33792);
    unsigned short* phi = (unsigned short*)sm;
    unsigned short* plo = (unsigned short*)(sm + 33792);
    float* ost = (float*)sm;
    float* redm = (float*)(sm + 67584);
    float* reds = (float*)(sm + 69632);

    int t = threadIdx.x;
    int lane = t & 63, w = t >> 6;
    int lrow = lane & 15, lgrp = lane >> 4;
    int wc = w * 32;

    int bid = blockIdx.x;
    int xcd = bid & 7, r = bid >> 3;
    int head = xcd * 64 + (r >> 2), rt = r & 3;
    float* qg = qo + ((size_t)head << 16) + rt * 64 * 256;
    const unsigned short* kh = khig + ((size_t)head << 16);
    const unsigned short* kl = klog + ((size_t)head << 16);
    const unsigned short* vth = vthig + ((size_t)head << 16);
    const unsigned short* vtl = vtlog + ((size_t)head << 16);

    // ---- stage q 64x256 fp32 -> bf16 hi/lo in LDS (once)
    {
        int row = t >> 3, cb = (t & 7) * 32;
        const float* qrow = qg + row * 256 + cb;
#pragma unroll
        for (int q4 = 0; q4 < 8; ++q4) {
            float4 v = *(const float4*)(qrow + q4 * 4);
            ushort4 hv, lv;
            hv.x = bf16_rn(v.x); lv.x = bf16_rn(v.x - bf16_f(hv.x));
            hv.y = bf16_rn(v.y); lv.y = bf16_rn(v.y - bf16_f(hv.y));
            hv.z = bf16_rn(v.z); lv.z = bf16_rn(v.z - bf16_f(hv.z));
            hv.w = bf16_rn(v.w); lv.w = bf16_rn(v.w - bf16_f(hv.w));
            *(ushort4*)&qhi[row * 264 + cb + q4 * 4] = hv;
            *(ushort4*)&qlo[row * 264 + cb + q4 * 4] = lv;
        }
    }
    __syncthreads();

    f32x4 acc[4][2];
#pragma unroll
    for (int mi = 0; mi < 4; ++mi)
#pragma unroll
        for (int nj = 0; nj < 2; ++nj) acc[mi][nj] = (f32x4){0.f, 0.f, 0.f, 0.f};

    // ---- phase 1: S = q k^T   (no barriers; B-frags straight from global/L2)
    for (int dc = 0; dc < 4; ++dc) {
#pragma unroll
        for (int kk = 0; kk < 2; ++kk) {
            int k0 = dc * 64 + kk * 32 + lgrp * 8;
            short8b bh[2], bl[2];
#pragma unroll
            for (int nj = 0; nj < 2; ++nj) {
                size_t go = (size_t)(wc + nj * 16 + lrow) * 256 + k0;
                bh[nj] = *(const short8b*)(kh + go);
                bl[nj] = *(const short8b*)(kl + go);
            }
#pragma unroll
            for (int mi = 0; mi < 4; ++mi) {
                short8b ah = *(short8b*)&qhi[(mi * 16 + lrow) * 264 + k0];
                short8b al = *(short8b*)&qlo[(mi * 16 + lrow) * 264 + k0];
#pragma unroll
                for (int nj = 0; nj < 2; ++nj) {
                    acc[mi][nj] = MFMA16(ah, bh[nj], acc[mi][nj], 0, 0, 0);
                    acc[mi][nj] = MFMA16(ah, bl[nj], acc[mi][nj], 0, 0, 0);
                    acc[mi][nj] = MFMA16(al, bh[nj], acc[mi][nj], 0, 0, 0);
                }
            }
        }
    }

    // ---- phase 2: softmax
#pragma unroll
    for (int mi = 0; mi < 4; ++mi)
#pragma unroll
        for (int nj = 0; nj < 2; ++nj) acc[mi][nj] *= 0.125f;

    float mx[4][4];
#pragma unroll
    for (int mi = 0; mi < 4; ++mi)
#pragma unroll
        for (int rr = 0; rr < 4; ++rr) {
            float m = fmaxf(acc[mi][0][rr], acc[mi][1][rr]);
            m = fmaxf(m, __shfl_xor(m, 1));
            m = fmaxf(m, __shfl_xor(m, 2));
            m = fmaxf(m, __shfl_xor(m, 4));
            m = fmaxf(m, __shfl_xor(m, 8));
            mx[mi][rr] = m;
        }
    if (lrow == 0) {
#pragma unroll
        for (int mi = 0; mi < 4; ++mi)
#pragma unroll
            for (int rr = 0; rr < 4; ++rr)
                redm[w * 64 + mi * 16 + lgrp * 4 + rr] = mx[mi][rr];
    }
    __syncthreads();   // redm ready; all q-frag reads done -> phi/plo may overwrite
    float invl[4][4];
#pragma unroll
    for (int mi = 0; mi < 4; ++mi)
#pragma unroll
        for (int rr = 0; rr < 4; ++rr) {
            int row = mi * 16 + lgrp * 4 + rr;
            float m = redm[row];
#pragma unroll
            for (int ww = 1; ww < 8; ++ww) m = fmaxf(m, redm[ww * 64 + row]);
            float p0 = __expf(acc[mi][0][rr] - m);
            float p1 = __expf(acc[mi][1][rr] - m);
            unsigned short h0 = bf16_rn(p0), h1 = bf16_rn(p1);
            phi[row * 264 + wc + lrow] = h0;
            phi[row * 264 + wc + 16 + lrow] = h1;
            plo[row * 264 + wc + lrow] = bf16_rn(p0 - bf16_f(h0));
            plo[row * 264 + wc + 16 + lrow] = bf16_rn(p1 - bf16_f(h1));
            float ls = p0 + p1;
            ls += __shfl_xor(ls, 1);
            ls += __shfl_xor(ls, 2);
            ls += __shfl_xor(ls, 4);
            ls += __shfl_xor(ls, 8);
            if (lrow == 0) reds[w * 64 + row] = ls;
        }
    __syncthreads();   // phi/plo + reds ready
#pragma unroll
    for (int mi = 0; mi < 4; ++mi)
#pragma unroll
        for (int rr = 0; rr < 4; ++rr) {
            int row = mi * 16 + lgrp * 4 + rr;
            float l = 0.f;
#pragma unroll
            for (int ww = 0; ww < 8; ++ww) l += reds[ww * 64 + row];
            invl[mi][rr] = 1.f / l;
        }

    // ---- phase 3: O = P V   (no barriers in loop; V-frags from global vt planes)
#pragma unroll
    for (int mi = 0; mi < 4; ++mi)
#pragma unroll
        for (int nd = 0; nd < 2; ++nd) acc[mi][nd] = (f32x4){0.f, 0.f, 0.f, 0.f};

    for (int jc = 0; jc < 8; ++jc) {
        int j0 = jc * 32 + lgrp * 8;
        short8b vh[2], vl[2];
#pragma unroll
        for (int nd = 0; nd < 2; ++nd) {
            size_t go = (size_t)(wc + nd * 16 + lrow) * 256 + j0;
            vh[nd] = *(const short8b*)(vth + go);
            vl[nd] = *(const short8b*)(vtl + go);
        }
#pragma unroll
        for (int mi = 0; mi < 4; ++mi) {
            short8b pa = *(short8b*)&phi[(mi * 16 + lrow) * 264 + j0];
            short8b pb = *(short8b*)&plo[(mi * 16 + lrow) * 264 + j0];
#pragma unroll
            for (int nd = 0; nd < 2; ++nd) {
                acc[mi][nd] = MFMA16(pa, vh[nd], acc[mi][nd], 0, 0, 0);
                acc[mi][nd] = MFMA16(pa, vl[nd], acc[mi][nd], 0, 0, 0);
                acc[mi][nd] = MFMA16(pb, vh[nd], acc[mi][nd], 0, 0, 0);
            }
        }
    }
    __syncthreads();   // all phi/plo reads done -> ost may overwrite

    // ---- epilogue
#pragma unroll
    for (int mi = 0; mi < 4; ++mi)
#pragma unroll
        for (int nd = 0; nd < 2; ++nd)
#pragma unroll
            for (int rr = 0; rr < 4; ++rr)
                ost[(mi * 16 + lgrp * 4 + rr) * 260 + wc + nd * 16 + lrow] =
                    acc[mi][nd][rr] * invl[mi][rr];
    __syncthreads();
#pragma unroll
    for (int it = 0; it < 8; ++it) {
        int id = it * 512 + t;
        int row = id >> 6, col4 = (id & 63) * 4;
        float4 vv = *(float4*)&ost[row * 260 + col4];
        *(float4*)(qg + row * 256 + col4) = vv;
    }
}

// ---------- kernel 6: final 1x1 conv (contiguous 64-float slices of planar O)
__global__ __launch_bounds__(256)
void convout_kernel(const float* __restrict__ in, const float* __restrict__ Wg,
                    const float* __restrict__ bias, float* __restrict__ out) {
    __shared__ float Wl[4096];
    __shared__ float xT[64][64];
    int t = threadIdx.x;
    for (int i = t; i < 4096; i += 256) Wl[i] = Wg[i];
    int p = t & 63, j = t >> 6;
    int pix = blockIdx.x * 64 + p;
    const float4* src = (const float4*)(in + (size_t)pix * 64 + j * 16);
#pragma unroll
    for (int q4 = 0; q4 < 4; ++q4) {
        float4 v = src[q4];
        int kk = j * 16 + q4 * 4;
        xT[kk][p] = v.x; xT[kk + 1][p] = v.y; xT[kk + 2][p] = v.z; xT[kk + 3][p] = v.w;
    }
    __syncthreads();
    float sv[64];
#pragma unroll
    for (int kk = 0; kk < 64; ++kk) sv[kk] = xT[kk][p];
    float acc[16];
#pragma unroll
    for (int u = 0; u < 16; ++u) {
        int c = j * 16 + u;
        float a = bias[c];
        const float4* wrow = (const float4*)(Wl + c * 64);
#pragma unroll
        for (int k4 = 0; k4 < 16; ++k4) {
            float4 w = wrow[k4];
            a += w.x * sv[4 * k4] + w.y * sv[4 * k4 + 1] + w.z * sv[4 * k4 + 2] + w.w * sv[4 * k4 + 3];
        }
        acc[u] = a;
    }
#pragma unroll
    for (int u = 0; u < 16; ++u) out[(size_t)pix * 64 + j * 16 + u] = acc[u];
}

extern "C" void kernel_launch(void* const* d_in, const int* in_sizes, int n_in,
                              void* d_out, int out_size, void* d_ws, size_t ws_size,
                              hipStream_t stream) {
    const float* x     = (const float*)d_in[0];
    const float* Wq    = (const float*)d_in[1];
    const float* bq    = (const float*)d_in[2];
    const float* Wk    = (const float*)d_in[3];
    const float* bk    = (const float*)d_in[4];
    const float* Wv    = (const float*)d_in[5];
    const float* bv    = (const float*)d_in[6];
    const float* Woff1 = (const float*)d_in[7];
    const float* boff1 = (const float*)d_in[8];
    const float* Woff2 = (const float*)d_in[9];
    const float* rpb   = (const float*)d_in[10];
    const float* Wout  = (const float*)d_in[11];
    const float* bout  = (const float*)d_in[12];
    float* out = (float*)d_out;

    char* wsb = (char*)d_ws;
    float* qbuf = (float*)wsb;                                        // 128MB (q -> O in place)
    unsigned short* khi = (unsigned short*)(wsb + (size_t)NPIX * 64 * 4);   // 64MB
    unsigned short* klo = khi + (size_t)NPIX * 64;                     // 64MB
    unsigned short* vhi = klo + (size_t)NPIX * 64;                     // 64MB (becomes vt in place)
    unsigned short* vlo = vhi + (size_t)NPIX * 64;                     // 64MB
    float* coords = (float*)(vlo + (size_t)NPIX * 64);                 // 4MB
    float* wcomb  = coords + (size_t)NPIX * 2;                         // 3200
    float* bcomb  = wcomb + 3200;                                      // 2
    float* wcat   = bcomb + 2;                                         // 8192
    float* bcat   = wcat + 8192;                                       // 128
    float* proj   = (float*)khi;   // 100MB scratch, consumed before khi/klo written

    build_wcomb_kernel<<<13, 256, 0, stream>>>(Woff1, boff1, Woff2, wcomb, bcomb);
    build_wcat_kernel<<<33, 256, 0, stream>>>(Wq, bq, wcomb, wcat, bcat);
    convqp_kernel<<<NPIX / 64, 256, 0, stream>>>(x, wcat, bcat, qbuf, proj);
    offset_gather_kernel<<<dim3(256, 8), 256, 0, stream>>>(proj, bcomb, (float2*)coords);
    sample_kv_kernel<<<NPIX / 64, 256, 0, stream>>>(x, (const float2*)coords, Wk, bk, Wv, bv,
                                                    rpb, khi, klo, vhi, vlo);
    vtrans_kernel<<<5120, 256, 0, stream>>>(vhi, vlo);
    attn_mfma_kernel<<<2048, 512, 0, stream>>>(qbuf, khi, klo, vhi, vlo);
    convout_kernel<<<NPIX / 64, 256, 0, stream>>>(qbuf, Wout, bout, out);
}

// Round 5
// 628.433 us; speedup vs baseline: 5.4169x; 1.4626x over previous
//
#include <hip/hip_runtime.h>
#include <math.h>

#define NPIX 524288   // 8*256*256

typedef __attribute__((ext_vector_type(8))) short short8b;
typedef __attribute__((ext_vector_type(4))) float f32x4;
#define MFMA16 __builtin_amdgcn_mfma_f32_16x16x32_bf16

__device__ inline unsigned short bf16_rn(float x) {
    unsigned u = __float_as_uint(x);
    unsigned r = (u + 0x7FFFu + ((u >> 16) & 1u)) >> 16;
    return (unsigned short)r;
}
__device__ inline float bf16_f(unsigned short h) {
    return __uint_as_float(((unsigned)h) << 16);
}
__device__ inline void split4(float a, float b, float c, float d, ushort4& hv, ushort4& lv) {
    hv.x = bf16_rn(a); lv.x = bf16_rn(a - bf16_f(hv.x));
    hv.y = bf16_rn(b); lv.y = bf16_rn(b - bf16_f(hv.y));
    hv.z = bf16_rn(c); lv.z = bf16_rn(c - bf16_f(hv.z));
    hv.w = bf16_rn(d); lv.w = bf16_rn(d - bf16_f(hv.w));
}

// ---------- kernel 1a: collapse offset head: Wcomb[p][cin][tap] = sum_c Woff2[p,c]*Woff1[c,cin,tap]
__global__ void build_wcomb_kernel(const float* __restrict__ Woff1,
                                   const float* __restrict__ boff1,
                                   const float* __restrict__ Woff2,
                                   float* __restrict__ wcomb,
                                   float* __restrict__ bcomb) {
    int idx = blockIdx.x * 256 + threadIdx.x;
    if (idx < 2 * 64 * 25) {
        int p = idx / 1600;
        int rest = idx - p * 1600;
        float s = 0.f;
        for (int cm = 0; cm < 64; ++cm)
            s += Woff2[p * 64 + cm] * Woff1[cm * 1600 + rest];
        wcomb[idx] = s;
    }
    if (idx < 2) {
        float s = 0.f;
        for (int cm = 0; cm < 64; ++cm) s += Woff2[idx * 64 + cm] * boff1[cm];
        bcomb[idx] = s;
    }
}

// ---------- kernel 1b: Wcat[128][64] = [Wq ; Wproj@Wq ; 0] as bf16 hi/lo planes + fp32 bcat
__global__ void build_wcat_kernel(const float* __restrict__ Wq, const float* __restrict__ bq,
                                  const float* __restrict__ wcomb,
                                  unsigned short* __restrict__ wcath,
                                  unsigned short* __restrict__ wcatl,
                                  float* __restrict__ bcat) {
    int idx = blockIdx.x * 256 + threadIdx.x;
    if (idx < 8192) {
        int r = idx >> 6, c = idx & 63;
        float v = 0.f;
        if (r < 64) v = Wq[r * 64 + c];
        else if (r < 114) {
            int ch = r - 64, p = ch / 25, tap = ch % 25;
            for (int cin = 0; cin < 64; ++cin)
                v += wcomb[p * 1600 + cin * 25 + tap] * Wq[cin * 64 + c];
        }
        unsigned short hh = bf16_rn(v);
        wcath[idx] = hh;
        wcatl[idx] = bf16_rn(v - bf16_f(hh));
    }
    if (idx >= 8192 && idx < 8192 + 128) {
        int r = idx - 8192;
        float v = 0.f;
        if (r < 64) v = bq[r];
        else if (r < 114) {
            int ch = r - 64, p = ch / 25, tap = ch % 25;
            for (int cin = 0; cin < 64; ++cin)
                v += wcomb[p * 1600 + cin * 25 + tap] * bq[cin];
        }
        bcat[r] = v;
    }
}

// ---------- kernel 1c: fixed weights -> bf16 hi/lo planes (wkv rows 0..63=k, 64..127=v; wout)
__global__ void build_wfixed_kernel(const float* __restrict__ Wk, const float* __restrict__ Wv,
                                    const float* __restrict__ Wout,
                                    unsigned short* __restrict__ wkvh, unsigned short* __restrict__ wkvl,
                                    unsigned short* __restrict__ wouth, unsigned short* __restrict__ woutl) {
    int idx = blockIdx.x * 256 + threadIdx.x;
    if (idx < 8192) {
        float v = (idx < 4096) ? Wk[idx] : Wv[idx - 4096];
        unsigned short hh = bf16_rn(v);
        wkvh[idx] = hh;
        wkvl[idx] = bf16_rn(v - bf16_f(hh));
    } else if (idx < 12288) {
        float v = Wout[idx - 8192];
        unsigned short hh = bf16_rn(v);
        wouth[idx - 8192] = hh;
        woutl[idx - 8192] = bf16_rn(v - bf16_f(hh));
    }
}

// ---------- kernel 2: fused q + proj conv via MFMA (M=64 pixels, N=128, K=64)
__global__ __launch_bounds__(256)
void convqp_kernel(const float* __restrict__ in, const unsigned short* __restrict__ wh,
                   const unsigned short* __restrict__ wl, const float* __restrict__ bcat,
                   float* __restrict__ qout, float* __restrict__ projout) {
    __shared__ unsigned short a_hi[64 * 72], a_lo[64 * 72];
    int t = threadIdx.x;
    int p = t & 63, w = t >> 6;
    int pix0 = blockIdx.x * 64;
    {
        const float4* src = (const float4*)(in + (size_t)(pix0 + p) * 64 + w * 16);
#pragma unroll
        for (int u4 = 0; u4 < 4; ++u4) {
            float4 v = src[u4];
            ushort4 hv, lv;
            split4(v.x, v.y, v.z, v.w, hv, lv);
            *(ushort4*)&a_hi[p * 72 + w * 16 + u4 * 4] = hv;
            *(ushort4*)&a_lo[p * 72 + w * 16 + u4 * 4] = lv;
        }
    }
    __syncthreads();
    int lrow = t & 15, lgrp = (t & 63) >> 4;
    int wc = w * 32;
    f32x4 acc[4][2];
#pragma unroll
    for (int mi = 0; mi < 4; ++mi)
#pragma unroll
        for (int nj = 0; nj < 2; ++nj) acc[mi][nj] = (f32x4){0.f, 0.f, 0.f, 0.f};
#pragma unroll
    for (int dk = 0; dk < 2; ++dk) {
        int k0 = dk * 32 + lgrp * 8;
        short8b bh[2], bl[2];
#pragma unroll
        for (int nj = 0; nj < 2; ++nj) {
            int c = wc + nj * 16 + lrow;
            bh[nj] = *(const short8b*)(wh + c * 64 + k0);
            bl[nj] = *(const short8b*)(wl + c * 64 + k0);
        }
#pragma unroll
        for (int mi = 0; mi < 4; ++mi) {
            int r = mi * 16 + lrow;
            short8b ah = *(short8b*)&a_hi[r * 72 + k0];
            short8b al = *(short8b*)&a_lo[r * 72 + k0];
#pragma unroll
            for (int nj = 0; nj < 2; ++nj) {
                acc[mi][nj] = MFMA16(ah, bh[nj], acc[mi][nj], 0, 0, 0);
                acc[mi][nj] = MFMA16(ah, bl[nj], acc[mi][nj], 0, 0, 0);
                acc[mi][nj] = MFMA16(al, bh[nj], acc[mi][nj], 0, 0, 0);
            }
        }
    }
    int b = pix0 >> 16, hw0 = pix0 & 65535;
#pragma unroll
    for (int nj = 0; nj < 2; ++nj) {
        int c = wc + nj * 16 + lrow;
        if (c < 114) {
            float bias = bcat[c];
            float* dst = (c < 64) ? (qout + (((size_t)(b * 64 + c)) << 16) + hw0)
                                  : (projout + (((size_t)(b * 50 + (c - 64))) << 16) + hw0);
#pragma unroll
            for (int mi = 0; mi < 4; ++mi) {
                float4 o;
                o.x = acc[mi][nj][0] + bias;
                o.y = acc[mi][nj][1] + bias;
                o.z = acc[mi][nj][2] + bias;
                o.w = acc[mi][nj][3] + bias;
                *(float4*)(dst + mi * 16 + lgrp * 4) = o;
            }
        }
    }
}

// ---------- kernel 3: offset via 25-tap shift-add over proj planes -> sample coords
__global__ __launch_bounds__(256)
void offset_gather_kernel(const float* __restrict__ proj, const float* __restrict__ bcomb,
                          float2* __restrict__ coords) {
    int x = threadIdx.x, y = blockIdx.x, b = blockIdx.y;
    const float* pb = proj + (((size_t)b * 50) << 16);
    float a0 = bcomb[0], a1 = bcomb[1];
#pragma unroll
    for (int ky = 0; ky < 5; ++ky) {
        int yy = y + ky - 2;
        if (yy < 0 || yy >= 256) continue;
#pragma unroll
        for (int kx = 0; kx < 5; ++kx) {
            int xx = x + kx - 2;
            if (xx < 0 || xx >= 256) continue;
            int tap = ky * 5 + kx;
            size_t off = (size_t)yy * 256 + xx;
            a0 += pb[((size_t)tap << 16) + off];
            a1 += pb[((size_t)(25 + tap) << 16) + off];
        }
    }
    float ox = tanhf(a0) * 5.f, oy = tanhf(a1) * 5.f;
    float vgx = (float)x + ox, vgy = (float)y + oy;
    float ix = vgx * (256.f / 255.f) - 0.5f;
    float iy = vgy * (256.f / 255.f) - 0.5f;
    coords[(((size_t)b) << 16) + y * 256 + x] = make_float2(ix, iy);
}

// ---------- kernel 4: bilinear sample + k/v convs via MFMA, emit bf16 hi/lo planes
__global__ __launch_bounds__(256)
void sample_kv_kernel(const float* __restrict__ x, const float2* __restrict__ coords,
                      const unsigned short* __restrict__ wh, const unsigned short* __restrict__ wl,
                      const float* __restrict__ bk, const float* __restrict__ bv,
                      const float* __restrict__ rpb,
                      unsigned short* __restrict__ khi, unsigned short* __restrict__ klo,
                      unsigned short* __restrict__ vhi, unsigned short* __restrict__ vlo) {
    __shared__ unsigned short a_hi[64 * 72], a_lo[64 * 72];
    int t = threadIdx.x;
    int p = t & 63, w = t >> 6;
    int pix0 = blockIdx.x * 64;
    int pix = pix0 + p;
    int b = pix0 >> 16, hw0 = pix0 & 65535, h = hw0 >> 8;
    {
        float2 cc = coords[pix];
        float ix0f = floorf(cc.x), iy0f = floorf(cc.y);
        float wx1 = cc.x - ix0f, wy1 = cc.y - iy0f;
        float wx0 = 1.f - wx1, wy0 = 1.f - wy1;
        int ix0 = (int)ix0f, iy0 = (int)iy0f;
        float s[16];
#pragma unroll
        for (int u = 0; u < 16; ++u) s[u] = 0.f;
        const float* xb = x + (((size_t)b) << 16) * 64 + w * 16;
        int cxs[4] = {ix0, ix0 + 1, ix0, ix0 + 1};
        int cys[4] = {iy0, iy0, iy0 + 1, iy0 + 1};
        float ws4[4] = {wx0 * wy0, wx1 * wy0, wx0 * wy1, wx1 * wy1};
#pragma unroll
        for (int cr = 0; cr < 4; ++cr) {
            int cx = cxs[cr], cy = cys[cr];
            if (cx >= 0 && cx < 256 && cy >= 0 && cy < 256) {
                float wgt = ws4[cr];
                const float4* sp = (const float4*)(xb + ((size_t)(cy * 256 + cx) << 6));
#pragma unroll
                for (int q4 = 0; q4 < 4; ++q4) {
                    float4 v = sp[q4];
                    s[4 * q4] += wgt * v.x; s[4 * q4 + 1] += wgt * v.y;
                    s[4 * q4 + 2] += wgt * v.z; s[4 * q4 + 3] += wgt * v.w;
                }
            }
        }
#pragma unroll
        for (int u4 = 0; u4 < 4; ++u4) {
            ushort4 hv, lv;
            split4(s[u4 * 4], s[u4 * 4 + 1], s[u4 * 4 + 2], s[u4 * 4 + 3], hv, lv);
            *(ushort4*)&a_hi[p * 72 + w * 16 + u4 * 4] = hv;
            *(ushort4*)&a_lo[p * 72 + w * 16 + u4 * 4] = lv;
        }
    }
    __syncthreads();
    int lrow = t & 15, lgrp = (t & 63) >> 4;
    int wc = w * 32;
    f32x4 acc[4][2];
#pragma unroll
    for (int mi = 0; mi < 4; ++mi)
#pragma unroll
        for (int nj = 0; nj < 2; ++nj) acc[mi][nj] = (f32x4){0.f, 0.f, 0.f, 0.f};
#pragma unroll
    for (int dk = 0; dk < 2; ++dk) {
        int k0 = dk * 32 + lgrp * 8;
        short8b bh[2], bl[2];
#pragma unroll
        for (int nj = 0; nj < 2; ++nj) {
            int c = wc + nj * 16 + lrow;
            bh[nj] = *(const short8b*)(wh + c * 64 + k0);
            bl[nj] = *(const short8b*)(wl + c * 64 + k0);
        }
#pragma unroll
        for (int mi = 0; mi < 4; ++mi) {
            int r = mi * 16 + lrow;
            short8b ah = *(short8b*)&a_hi[r * 72 + k0];
            short8b al = *(short8b*)&a_lo[r * 72 + k0];
#pragma unroll
            for (int nj = 0; nj < 2; ++nj) {
                acc[mi][nj] = MFMA16(ah, bh[nj], acc[mi][nj], 0, 0, 0);
                acc[mi][nj] = MFMA16(ah, bl[nj], acc[mi][nj], 0, 0, 0);
                acc[mi][nj] = MFMA16(al, bh[nj], acc[mi][nj], 0, 0, 0);
            }
        }
    }
#pragma unroll
    for (int nj = 0; nj < 2; ++nj) {
        int c = wc + nj * 16 + lrow;
        float bias;
        unsigned short *dh, *dl;
        if (c < 64) { bias = bk[c]; dh = khi; dl = klo; }
        else        { bias = bv[c - 64] + rpb[(c - 64) * 256 + h]; dh = vhi; dl = vlo; }
        size_t o = (((size_t)(b * 64 + (c & 63))) << 16) + hw0;
#pragma unroll
        for (int mi = 0; mi < 4; ++mi) {
            float v0 = acc[mi][nj][0] + bias;
            float v1 = acc[mi][nj][1] + bias;
            float v2 = acc[mi][nj][2] + bias;
            float v3 = acc[mi][nj][3] + bias;
            ushort4 hv, lv;
            split4(v0, v1, v2, v3, hv, lv);
            *(ushort4*)(dh + o + mi * 16 + lgrp * 4) = hv;
            *(ushort4*)(dl + o + mi * 16 + lgrp * 4) = lv;
        }
    }
}

// ---------- kernel 4b: in-place paired-tile transpose of v hi/lo planes ([head][j][d] -> [head][d][j])
__global__ __launch_bounds__(256)
void vtrans_kernel(unsigned short* __restrict__ vhi, unsigned short* __restrict__ vlo) {
    __shared__ unsigned short T1[64][72];
    __shared__ unsigned short T2[64][72];
    const int ti_tab[10] = {0, 0, 0, 0, 1, 1, 1, 2, 2, 3};
    const int tj_tab[10] = {0, 1, 2, 3, 1, 2, 3, 2, 3, 3};
    int head = blockIdx.x / 10, pidx = blockIdx.x - head * 10;
    int ti = ti_tab[pidx], tj = tj_tab[pidx];
    int t = threadIdx.x;
    int r = t >> 2, cs = (t & 3) * 16;
    bool diag = (ti == tj);
#pragma unroll
    for (int pl = 0; pl < 2; ++pl) {
        unsigned short* base = (pl ? vlo : vhi) + ((size_t)head << 16);
        *(short8b*)&T1[r][cs]     = *(const short8b*)(base + (size_t)(ti * 64 + r) * 256 + tj * 64 + cs);
        *(short8b*)&T1[r][cs + 8] = *(const short8b*)(base + (size_t)(ti * 64 + r) * 256 + tj * 64 + cs + 8);
        if (!diag) {
            *(short8b*)&T2[r][cs]     = *(const short8b*)(base + (size_t)(tj * 64 + r) * 256 + ti * 64 + cs);
            *(short8b*)&T2[r][cs + 8] = *(const short8b*)(base + (size_t)(tj * 64 + r) * 256 + ti * 64 + cs + 8);
        }
        __syncthreads();
        {
            short8b o0, o1;
#pragma unroll
            for (int u = 0; u < 8; ++u) { o0[u] = (short)T1[cs + u][r]; o1[u] = (short)T1[cs + 8 + u][r]; }
            *(short8b*)(base + (size_t)(tj * 64 + r) * 256 + ti * 64 + cs) = o0;
            *(short8b*)(base + (size_t)(tj * 64 + r) * 256 + ti * 64 + cs + 8) = o1;
            if (!diag) {
#pragma unroll
                for (int u = 0; u < 8; ++u) { o0[u] = (short)T2[cs + u][r]; o1[u] = (short)T2[cs + 8 + u][r]; }
                *(short8b*)(base + (size_t)(ti * 64 + r) * 256 + tj * 64 + cs) = o0;
                *(short8b*)(base + (size_t)(ti * 64 + r) * 256 + tj * 64 + cs + 8) = o1;
            }
        }
        __syncthreads();
    }
}

// ---------- kernel 5: MFMA attention; k/v fragments direct from global bf16 planes
__global__ __launch_bounds__(512, 4)
void attn_mfma_kernel(float* __restrict__ qo,
                      const unsigned short* __restrict__ khig, const unsigned short* __restrict__ klog,
                      const unsigned short* __restrict__ vthig, const unsigned short* __restrict__ vtlog) {
    __shared__ char sm[71680];
    unsigned short* qhi = (unsigned short*)sm;
    unsigned short* qlo = (unsigned short*)(sm + 33792);
    unsigned short* phi = (unsigned short*)sm;
    unsigned short* plo = (unsigned short*)(sm + 33792);
    float* ost = (float*)sm;
    float* redm = (float*)(sm + 67584);
    float* reds = (float*)(sm + 69632);

    int t = threadIdx.x;
    int lane = t & 63, w = t >> 6;
    int lrow = lane & 15, lgrp = lane >> 4;
    int wc = w * 32;

    int bid = blockIdx.x;
    int xcd = bid & 7, r = bid >> 3;
    int head = xcd * 64 + (r >> 2), rt = r & 3;
    float* qg = qo + ((size_t)head << 16) + rt * 64 * 256;
    const unsigned short* kh = khig + ((size_t)head << 16);
    const unsigned short* kl = klog + ((size_t)head << 16);
    const unsigned short* vth = vthig + ((size_t)head << 16);
    const unsigned short* vtl = vtlog + ((size_t)head << 16);

    {
        int row = t >> 3, cb = (t & 7) * 32;
        const float* qrow = qg + row * 256 + cb;
#pragma unroll
        for (int q4 = 0; q4 < 8; ++q4) {
            float4 v = *(const float4*)(qrow + q4 * 4);
            ushort4 hv, lv;
            split4(v.x, v.y, v.z, v.w, hv, lv);
            *(ushort4*)&qhi[row * 264 + cb + q4 * 4] = hv;
            *(ushort4*)&qlo[row * 264 + cb + q4 * 4] = lv;
        }
    }
    __syncthreads();

    f32x4 acc[4][2];
#pragma unroll
    for (int mi = 0; mi < 4; ++mi)
#pragma unroll
        for (int nj = 0; nj < 2; ++nj) acc[mi][nj] = (f32x4){0.f, 0.f, 0.f, 0.f};

    for (int dc = 0; dc < 4; ++dc) {
#pragma unroll
        for (int kk = 0; kk < 2; ++kk) {
            int k0 = dc * 64 + kk * 32 + lgrp * 8;
            short8b bh[2], bl[2];
#pragma unroll
            for (int nj = 0; nj < 2; ++nj) {
                size_t go = (size_t)(wc + nj * 16 + lrow) * 256 + k0;
                bh[nj] = *(const short8b*)(kh + go);
                bl[nj] = *(const short8b*)(kl + go);
            }
#pragma unroll
            for (int mi = 0; mi < 4; ++mi) {
                short8b ah = *(short8b*)&qhi[(mi * 16 + lrow) * 264 + k0];
                short8b al = *(short8b*)&qlo[(mi * 16 + lrow) * 264 + k0];
#pragma unroll
                for (int nj = 0; nj < 2; ++nj) {
                    acc[mi][nj] = MFMA16(ah, bh[nj], acc[mi][nj], 0, 0, 0);
                    acc[mi][nj] = MFMA16(ah, bl[nj], acc[mi][nj], 0, 0, 0);
                    acc[mi][nj] = MFMA16(al, bh[nj], acc[mi][nj], 0, 0, 0);
                }
            }
        }
    }

#pragma unroll
    for (int mi = 0; mi < 4; ++mi)
#pragma unroll
        for (int nj = 0; nj < 2; ++nj) acc[mi][nj] *= 0.125f;

    float mx[4][4];
#pragma unroll
    for (int mi = 0; mi < 4; ++mi)
#pragma unroll
        for (int rr = 0; rr < 4; ++rr) {
            float m = fmaxf(acc[mi][0][rr], acc[mi][1][rr]);
            m = fmaxf(m, __shfl_xor(m, 1));
            m = fmaxf(m, __shfl_xor(m, 2));
            m = fmaxf(m, __shfl_xor(m, 4));
            m = fmaxf(m, __shfl_xor(m, 8));
            mx[mi][rr] = m;
        }
    if (lrow == 0) {
#pragma unroll
        for (int mi = 0; mi < 4; ++mi)
#pragma unroll
            for (int rr = 0; rr < 4; ++rr)
                redm[w * 64 + mi * 16 + lgrp * 4 + rr] = mx[mi][rr];
    }
    __syncthreads();
    float invl[4][4];
#pragma unroll
    for (int mi = 0; mi < 4; ++mi)
#pragma unroll
        for (int rr = 0; rr < 4; ++rr) {
            int row = mi * 16 + lgrp * 4 + rr;
            float m = redm[row];
#pragma unroll
            for (int ww = 1; ww < 8; ++ww) m = fmaxf(m, redm[ww * 64 + row]);
            float p0 = __expf(acc[mi][0][rr] - m);
            float p1 = __expf(acc[mi][1][rr] - m);
            unsigned short h0 = bf16_rn(p0), h1 = bf16_rn(p1);
            phi[row * 264 + wc + lrow] = h0;
            phi[row * 264 + wc + 16 + lrow] = h1;
            plo[row * 264 + wc + lrow] = bf16_rn(p0 - bf16_f(h0));
            plo[row * 264 + wc + 16 + lrow] = bf16_rn(p1 - bf16_f(h1));
            float ls = p0 + p1;
            ls += __shfl_xor(ls, 1);
            ls += __shfl_xor(ls, 2);
            ls += __shfl_xor(ls, 4);
            ls += __shfl_xor(ls, 8);
            if (lrow == 0) reds[w * 64 + row] = ls;
        }
    __syncthreads();
#pragma unroll
    for (int mi = 0; mi < 4; ++mi)
#pragma unroll
        for (int rr = 0; rr < 4; ++rr) {
            int row = mi * 16 + lgrp * 4 + rr;
            float l = 0.f;
#pragma unroll
            for (int ww = 0; ww < 8; ++ww) l += reds[ww * 64 + row];
            invl[mi][rr] = 1.f / l;
        }

#pragma unroll
    for (int mi = 0; mi < 4; ++mi)
#pragma unroll
        for (int nd = 0; nd < 2; ++nd) acc[mi][nd] = (f32x4){0.f, 0.f, 0.f, 0.f};

    for (int jc = 0; jc < 8; ++jc) {
        int j0 = jc * 32 + lgrp * 8;
        short8b vh[2], vl[2];
#pragma unroll
        for (int nd = 0; nd < 2; ++nd) {
            size_t go = (size_t)(wc + nd * 16 + lrow) * 256 + j0;
            vh[nd] = *(const short8b*)(vth + go);
            vl[nd] = *(const short8b*)(vtl + go);
        }
#pragma unroll
        for (int mi = 0; mi < 4; ++mi) {
            short8b pa = *(short8b*)&phi[(mi * 16 + lrow) * 264 + j0];
            short8b pb = *(short8b*)&plo[(mi * 16 + lrow) * 264 + j0];
#pragma unroll
            for (int nd = 0; nd < 2; ++nd) {
                acc[mi][nd] = MFMA16(pa, vh[nd], acc[mi][nd], 0, 0, 0);
                acc[mi][nd] = MFMA16(pa, vl[nd], acc[mi][nd], 0, 0, 0);
                acc[mi][nd] = MFMA16(pb, vh[nd], acc[mi][nd], 0, 0, 0);
            }
        }
    }
    __syncthreads();

#pragma unroll
    for (int mi = 0; mi < 4; ++mi)
#pragma unroll
        for (int nd = 0; nd < 2; ++nd)
#pragma unroll
            for (int rr = 0; rr < 4; ++rr)
                ost[(mi * 16 + lgrp * 4 + rr) * 260 + wc + nd * 16 + lrow] =
                    acc[mi][nd][rr] * invl[mi][rr];
    __syncthreads();
#pragma unroll
    for (int it = 0; it < 8; ++it) {
        int id = it * 512 + t;
        int row = id >> 6, col4 = (id & 63) * 4;
        float4 vv = *(float4*)&ost[row * 260 + col4];
        *(float4*)(qg + row * 256 + col4) = vv;
    }
}

// ---------- kernel 6: final 1x1 conv via MFMA (flat [pix][64] in/out, M=64, N=64, K=64)
__global__ __launch_bounds__(256)
void convout_kernel(const float* __restrict__ in, const unsigned short* __restrict__ wh,
                    const unsigned short* __restrict__ wl, const float* __restrict__ bias,
                    float* __restrict__ out) {
    __shared__ unsigned short a_hi[64 * 72], a_lo[64 * 72];
    int t = threadIdx.x;
    int p = t & 63, w = t >> 6;
    int pix0 = blockIdx.x * 64;
    {
        const float4* src = (const float4*)(in + (size_t)(pix0 + p) * 64 + w * 16);
#pragma unroll
        for (int u4 = 0; u4 < 4; ++u4) {
            float4 v = src[u4];
            ushort4 hv, lv;
            split4(v.x, v.y, v.z, v.w, hv, lv);
            *(ushort4*)&a_hi[p * 72 + w * 16 + u4 * 4] = hv;
            *(ushort4*)&a_lo[p * 72 + w * 16 + u4 * 4] = lv;
        }
    }
    __syncthreads();
    int lrow = t & 15, lgrp = (t & 63) >> 4;
    int c = w * 16 + lrow;
    f32x4 acc[4];
#pragma unroll
    for (int mi = 0; mi < 4; ++mi) acc[mi] = (f32x4){0.f, 0.f, 0.f, 0.f};
#pragma unroll
    for (int dk = 0; dk < 2; ++dk) {
        int k0 = dk * 32 + lgrp * 8;
        short8b bh = *(const short8b*)(wh + c * 64 + k0);
        short8b bl = *(const short8b*)(wl + c * 64 + k0);
#pragma unroll
        for (int mi = 0; mi < 4; ++mi) {
            int r = mi * 16 + lrow;
            short8b ah = *(short8b*)&a_hi[r * 72 + k0];
            short8b al = *(short8b*)&a_lo[r * 72 + k0];
            acc[mi] = MFMA16(ah, bh, acc[mi], 0, 0, 0);
            acc[mi] = MFMA16(ah, bl, acc[mi], 0, 0, 0);
            acc[mi] = MFMA16(al, bh, acc[mi], 0, 0, 0);
        }
    }
    float bb = bias[c];
#pragma unroll
    for (int mi = 0; mi < 4; ++mi) {
        int px0 = pix0 + mi * 16 + lgrp * 4;
#pragma unroll
        for (int rr = 0; rr < 4; ++rr)
            out[(size_t)(px0 + rr) * 64 + c] = acc[mi][rr] + bb;
    }
}

extern "C" void kernel_launch(void* const* d_in, const int* in_sizes, int n_in,
                              void* d_out, int out_size, void* d_ws, size_t ws_size,
                              hipStream_t stream) {
    const float* x     = (const float*)d_in[0];
    const float* Wq    = (const float*)d_in[1];
    const float* bq    = (const float*)d_in[2];
    const float* Wk    = (const float*)d_in[3];
    const float* bk    = (const float*)d_in[4];
    const float* Wv    = (const float*)d_in[5];
    const float* bv    = (const float*)d_in[6];
    const float* Woff1 = (const float*)d_in[7];
    const float* boff1 = (const float*)d_in[8];
    const float* Woff2 = (const float*)d_in[9];
    const float* rpb   = (const float*)d_in[10];
    const float* Wout  = (const float*)d_in[11];
    const float* bout  = (const float*)d_in[12];
    float* out = (float*)d_out;

    char* wsb = (char*)d_ws;
    float* qbuf = (float*)wsb;                                          // 128MB (q -> O in place)
    unsigned short* khi = (unsigned short*)(wsb + (size_t)NPIX * 64 * 4);
    unsigned short* klo = khi + (size_t)NPIX * 64;
    unsigned short* vhi = klo + (size_t)NPIX * 64;
    unsigned short* vlo = vhi + (size_t)NPIX * 64;
    float* coords = (float*)(vlo + (size_t)NPIX * 64);                  // 4MB
    float* wcomb  = coords + (size_t)NPIX * 2;                          // 3200
    float* bcomb  = wcomb + 3200;                                       // 2
    float* bcat   = bcomb + 2;                                          // 128
    unsigned short* wcath = (unsigned short*)(bcat + 128);              // 8192
    unsigned short* wcatl = wcath + 8192;
    unsigned short* wkvh  = wcatl + 8192;                               // 8192
    unsigned short* wkvl  = wkvh + 8192;
    unsigned short* wouth = wkvl + 8192;                                // 4096
    unsigned short* woutl = wouth + 4096;
    float* proj = (float*)khi;   // 100MB scratch (khi+klo region), consumed before k written

    build_wcomb_kernel<<<13, 256, 0, stream>>>(Woff1, boff1, Woff2, wcomb, bcomb);
    build_wcat_kernel<<<33, 256, 0, stream>>>(Wq, bq, wcomb, wcath, wcatl, bcat);
    build_wfixed_kernel<<<48, 256, 0, stream>>>(Wk, Wv, Wout, wkvh, wkvl, wouth, woutl);
    convqp_kernel<<<NPIX / 64, 256, 0, stream>>>(x, wcath, wcatl, bcat, qbuf, proj);
    offset_gather_kernel<<<dim3(256, 8), 256, 0, stream>>>(proj, bcomb, (float2*)coords);
    sample_kv_kernel<<<NPIX / 64, 256, 0, stream>>>(x, (const float2*)coords, wkvh, wkvl,
                                                    bk, bv, rpb, khi, klo, vhi, vlo);
    vtrans_kernel<<<5120, 256, 0, stream>>>(vhi, vlo);
    attn_mfma_kernel<<<2048, 512, 0, stream>>>(qbuf, khi, klo, vhi, vlo);
    convout_kernel<<<NPIX / 64, 256, 0, stream>>>(qbuf, wouth, woutl, bout, out);
}